// Round 7
// baseline (141.713 us; speedup 1.0000x reference)
//
#include <hip/hip_runtime.h>

#define DCH   768
#define NHALF 8192
#define NTH   512
#define PHYS(i) ((i) + ((i) >> 4))
// LDS layout (v2f units): tab1k [0,1024) | t64 [1024,1088) | z [1088, 1088+8704)
#define T64O  1024
#define ZOFF  1088
#define LDSE  (ZOFF + NHALF + NHALF / 16)   // 9792 v2f = 78336 B
#define NFULL 16384
#define NTH2  1024
#define LDSE2 (NFULL + NFULL / 16)          // fallback: 17408 v2f

#define C1F 0.9238795325112867f        // cos(pi/8)
#define S1F 0.3826834323650898f        // sin(pi/8)
#define C2F 0.7071067811865476f        // cos(pi/4)

typedef float v2f __attribute__((ext_vector_type(2)));

__device__ __forceinline__ v2f mk(float x, float y) { v2f r; r.x = x; r.y = y; return r; }
// complex multiply (compiler codegen; verified round-5 form)
__device__ __forceinline__ v2f cmul(v2f a, v2f b) {
    v2f re = a.xx * b;                       // {ax*bx, ax*by}
    return __builtin_elementwise_fma(mk(-a.y, a.y), mk(b.y, b.x), re);
}
__device__ __forceinline__ v2f mnegi(v2f t) { return mk(t.y, -t.x); }   // -i*t
__device__ __forceinline__ v2f wtw(float rev) {   // e^{2*pi*i*rev}
    return mk(__builtin_amdgcn_cosf(rev), __builtin_amdgcn_sinf(rev));
}
__device__ __forceinline__ int drev8(int v) {        // 4-digit base-4 reversal of 8-bit
    return ((v & 3) << 6) | ((v & 12) << 2) | ((v >> 2) & 12) | ((v >> 6) & 3);
}
__device__ __forceinline__ constexpr int rev2i(int a) { return ((a & 3) << 2) | ((a >> 2) & 3); }
__device__ __forceinline__ constexpr int rtof(int t)  { return ((t & 3) << 2) | (t >> 2); }

__device__ __forceinline__ v2f Ktw(int rt) {      // e^{-2*pi*i*rt/32}
    const float KC[16] = {1.0f, 0.980785280f, 0.923879533f, 0.831469612f,
                          0.707106781f, 0.555570233f, 0.382683432f, 0.195090322f,
                          0.0f, -0.195090322f, -0.382683432f, -0.555570233f,
                          -0.707106781f, -0.831469612f, -0.923879533f, -0.980785280f};
    const float KS[16] = {0.0f, -0.195090322f, -0.382683432f, -0.555570233f,
                          -0.707106781f, -0.831469612f, -0.923879533f, -0.980785280f,
                          -1.0f, -0.980785280f, -0.923879533f, -0.831469612f,
                          -0.707106781f, -0.555570233f, -0.382683432f, -0.195090322f};
    return mk(KC[rt], KS[rt]);
}

// ======== table-driven fused radix-16 (two radix-4 levels) ========
// T has unit e^{-2*pi*i/(16*M2)}; forward index n, inverse index (-n)&NMASK (= conj).
template<int M2, int NMASK, bool INV>
__device__ __forceinline__ void bfly16(v2f* a, const v2f* __restrict__ T, const int j) {
#define TW(n) (T[INV ? ((-(n)) & NMASK) : (n)])
    const v2f V1 = TW(4 * j), V2 = TW(8 * j), V3 = TW(12 * j);
    if (!INV) {
#pragma unroll
        for (int ai = 0; ai < 4; ++ai) {
            const int jc = j + M2 * ai;
            const v2f w1 = TW(jc), w2 = TW(2 * jc), w3 = TW(3 * jc);
            v2f u0 = a[ai], u1 = a[ai + 4], u2 = a[ai + 8], u3 = a[ai + 12];
            v2f t0 = u0 + u2, t1 = u1 + u3;
            v2f t2 = u0 - u2, t3 = u1 - u3;
            v2f mi3 = mnegi(t3);
            a[ai]      = t0 + t1;
            a[ai + 4]  = cmul(t2 + mi3, w1);
            a[ai + 8]  = cmul(t0 - t1, w2);
            a[ai + 12] = cmul(t2 - mi3, w3);
        }
#pragma unroll
        for (int p = 0; p < 4; ++p) {
            v2f u0 = a[4 * p], u1 = a[4 * p + 1], u2 = a[4 * p + 2], u3 = a[4 * p + 3];
            v2f t0 = u0 + u2, t1 = u1 + u3;
            v2f t2 = u0 - u2, t3 = u1 - u3;
            v2f mi3 = mnegi(t3);
            a[4 * p]     = t0 + t1;
            a[4 * p + 1] = cmul(t2 + mi3, V1);
            a[4 * p + 2] = cmul(t0 - t1, V2);
            a[4 * p + 3] = cmul(t2 - mi3, V3);
        }
    } else {
#pragma unroll
        for (int p = 0; p < 4; ++p) {
            v2f b0 = a[4 * p];
            v2f b1 = cmul(a[4 * p + 1], V1);
            v2f b2 = cmul(a[4 * p + 2], V2);
            v2f b3 = cmul(a[4 * p + 3], V3);
            v2f t0 = b0 + b2, t1 = b0 - b2;
            v2f t2 = b1 + b3;
            v2f dd = b3 - b1;
            v2f t3 = mnegi(dd);
            a[4 * p]     = t0 + t2;
            a[4 * p + 1] = t1 + t3;
            a[4 * p + 2] = t0 - t2;
            a[4 * p + 3] = t1 - t3;
        }
#pragma unroll
        for (int ai = 0; ai < 4; ++ai) {
            const int jc = j + M2 * ai;
            const v2f w1 = TW(jc), w2 = TW(2 * jc), w3 = TW(3 * jc);
            v2f b0 = a[ai];
            v2f b1 = cmul(a[ai + 4], w1);
            v2f b2 = cmul(a[ai + 8], w2);
            v2f b3 = cmul(a[ai + 12], w3);
            v2f t0 = b0 + b2, t1 = b0 - b2;
            v2f t2 = b1 + b3;
            v2f dd = b3 - b1;
            v2f t3 = mnegi(dd);
            a[ai]      = t0 + t2;
            a[ai + 4]  = t1 + t3;
            a[ai + 8]  = t0 - t2;
            a[ai + 12] = t1 - t3;
        }
    }
#undef TW
}

__device__ __forceinline__ void fwd4x4(v2f* a) {   // radix-4 DIF, m=1, twiddle-free
#pragma unroll
    for (int u = 0; u < 4; ++u) {
        v2f u0 = a[4*u], u1 = a[4*u+1], u2 = a[4*u+2], u3 = a[4*u+3];
        v2f t0 = u0 + u2, t1 = u1 + u3, t2 = u0 - u2, t3 = u1 - u3;
        v2f mi3 = mnegi(t3);
        a[4*u] = t0 + t1; a[4*u+1] = t2 + mi3;
        a[4*u+2] = t0 - t1; a[4*u+3] = t2 - mi3;
    }
}
__device__ __forceinline__ void inv4x4(v2f* a) {   // inverse radix-4, m=1
#pragma unroll
    for (int u = 0; u < 4; ++u) {
        v2f b0 = a[4*u], b1 = a[4*u+1], b2 = a[4*u+2], b3 = a[4*u+3];
        v2f t0 = b0 + b2, t1 = b0 - b2, t2 = b1 + b3;
        v2f dd = b3 - b1;
        v2f t3 = mnegi(dd);
        a[4*u] = t0 + t2; a[4*u+1] = t1 + t3;
        a[4*u+2] = t0 - t2; a[4*u+3] = t1 - t3;
    }
}

// Forward 8192-pt complex FFT of src (4096 nonzero v2f, top half zero).
// lds = raw dynamic-LDS base; builds twiddle tables; z at lds+ZOFF.
__device__ __forceinline__ void fwd8k(const v2f* __restrict__ src,
                                      v2f* __restrict__ lds, const int w, v2f* a) {
    v2f* __restrict__ tb  = lds;          // 1024 entries, unit 1/1024
    v2f* __restrict__ t64 = lds + T64O;   // 64 entries, unit 1/64
    v2f* __restrict__ z   = lds + ZOFF;
    const float R2 = 0.70710678118654752f;
    // ---- table build (completes before the P1 barrier)
    tb[w]       = wtw(-(float)w * (1.0f / 1024.0f));
    tb[w + 512] = wtw(-(float)(w + 512) * (1.0f / 1024.0f));
    if (w < 64) t64[w] = wtw(-(float)w * (1.0f / 64.0f));
    // ---- P1: radix-2(m=4096, top half zero) + radix-4(m=1024) from global
#pragma unroll
    for (int g = 0; g < 2; ++g) {
        const int i0 = w + 512 * g;
        v2f c0 = src[i0], c1 = src[i0 + 1024], c2 = src[i0 + 2048], c3 = src[i0 + 3072];
        const v2f wA  = wtw(-(float)i0 * (1.0f / 8192.0f));
        const v2f wB  = cmul(wA, wA);
        const v2f wB2 = cmul(wB, wB);
        const v2f wB3 = cmul(wB2, wB);
        const int pb = PHYS(i0);
        v2f t0 = c0 + c2, t1 = c1 + c3, t2 = c0 - c2, t3 = c1 - c3;
        v2f mi3 = mnegi(t3);
        z[pb]            = t0 + t1;
        z[pb + 1088]     = cmul(t2 + mi3, wB);
        z[pb + 2 * 1088] = cmul(t0 - t1, wB2);
        z[pb + 3 * 1088] = cmul(t2 - mi3, wB3);
        v2f d0 = cmul(c0, wA);
        v2f d1 = cmul(c1, cmul(wA, mk(R2, -R2)));
        v2f d2 = cmul(c2, mk(wA.y, -wA.x));           // -i*wA
        v2f d3 = cmul(c3, cmul(wA, mk(-R2, -R2)));
        t0 = d0 + d2; t1 = d1 + d3; t2 = d0 - d2; t3 = d1 - d3;
        mi3 = mnegi(t3);
        z[pb + 4 * 1088] = t0 + t1;
        z[pb + 5 * 1088] = cmul(t2 + mi3, wB);
        z[pb + 6 * 1088] = cmul(t0 - t1, wB2);
        z[pb + 7 * 1088] = cmul(t2 - mi3, wB3);
    }
    __syncthreads();
    // ---- P2: radix-16, m2 = 64 (tab1k)
    {
        const int j = w & 63, blk = w >> 6;
        const int base = PHYS(blk * 1024 + j);
#pragma unroll
        for (int t = 0; t < 16; ++t) a[t] = z[base + 68 * t];
        bfly16<64, 1023, false>(a, tb, j);
#pragma unroll
        for (int t = 0; t < 16; ++t) z[base + 68 * t] = a[t];
    }
    __syncthreads();
    // ---- P3: radix-16, m2 = 4 (t64)
    {
        const int j = w & 3, g = w >> 2;
        const int i0 = g * 64 + j;
#pragma unroll
        for (int t = 0; t < 16; ++t) a[t] = z[PHYS(i0 + 4 * t)];
        bfly16<4, 63, false>(a, t64, j);
#pragma unroll
        for (int t = 0; t < 16; ++t) z[PHYS(i0 + 4 * t)] = a[t];
    }
    __syncthreads();
    // ---- P4a: final radix-4 (m=1) in regs, publish C
    {
        const int base = 17 * w;
#pragma unroll
        for (int t = 0; t < 16; ++t) a[t] = z[base + t];
        fwd4x4(a);
#pragma unroll
        for (int t = 0; t < 16; ++t) z[base + t] = a[t];
    }
    __syncthreads();
}

// ============ kernel 1: per-channel H spectrum, scaled by 0.5/N, H += B
extern "C" __global__ void __launch_bounds__(NTH, 4)
hspec_kernel(const float* __restrict__ hg, const float* __restrict__ bg,
             float* __restrict__ wsHf, float* __restrict__ wsNy) {
    extern __shared__ v2f lds[];
    v2f* __restrict__ z = lds + ZOFF;
    const int w = threadIdx.x;
    const int d = blockIdx.x;
    const v2f* hr = (const v2f*)hg + (size_t)d * 4096;
    v2f a[16];
    fwd8k(hr, lds, w, a);

    const float Bd = bg[d];
    const float invN = 1.0f / 16384.0f;
    v2f* out = (v2f*)wsHf + (size_t)d * NHALF;
    const int wm = w & 255, whi = w >> 8;
    const int k0 = 2 * drev8(wm) + whi;
    const v2f wk0 = wtw(-(float)k0 * (1.0f / 16384.0f));
    int qm = 0;
    if (w != 0) { const int bq = (512 - k0) >> 1; qm = (whi << 8) | drev8(bq); }
#pragma unroll
    for (int t = 0; t < 16; ++t) {
        const int rt = rtof(t);
        if (w == 0 && t == 0) {
            v2f C0 = a[0];
            out[0] = mk((C0.x + C0.y + Bd) * invN, 0.0f);
            ((v2f*)wsNy)[d] = mk((C0.x - C0.y + Bd) * invN, 0.0f);
        } else {
            const int cq = (w == 0) ? rev2i(16 - rt) : rev2i(15 - rt);
            const v2f Cq = z[17 * qm + cq];
            const v2f Cp = a[t];
            const v2f cA = mk(0.5f * (Cp.x + Cq.x), 0.5f * (Cp.y - Cq.y));
            const v2f cB = mk(0.5f * (Cp.y + Cq.y), -0.5f * (Cp.x - Cq.x));
            const v2f Wk = cmul(wk0, Ktw(rt));
            const v2f Hf = cA + cmul(Wk, cB);
            out[(t << 9) + w] = mk((Hf.x + Bd) * invN, Hf.y * invN);
        }
    }
}

// ============ kernel 2: main conv
extern "C" __global__ void __launch_bounds__(NTH, 4)
fftconv_main(const float* __restrict__ xg, const float* __restrict__ wsHf,
             const float* __restrict__ wsNy, float* __restrict__ yg) {
    extern __shared__ v2f lds[];
    v2f* __restrict__ tb  = lds;
    v2f* __restrict__ t64 = lds + T64O;
    v2f* __restrict__ z   = lds + ZOFF;
    const int w = threadIdx.x;
    const int bid = blockIdx.x;
    const int d = bid >> 2, b = bid & 3;
    const v2f* xr = (const v2f*)xg + (size_t)(b * DCH + d) * 4096;
    const v2f* hrow = (const v2f*)wsHf + (size_t)d * NHALF;
    const float R2 = 0.70710678118654752f;
    v2f a[16];
    fwd8k(xr, lds, w, a);

    // ---- P4b: pair-owner combine; owner Wtil stays in regs, partner to LDS
    {
        const int wm = w & 255, whi = w >> 8;
        const int k0 = 2 * drev8(wm) + whi;
        const v2f wk0 = wtw(-(float)k0 * (1.0f / 16384.0f));
        int qm = 0;
        if (w != 0) { const int bq = (512 - k0) >> 1; qm = (whi << 8) | drev8(bq); }
#pragma unroll
        for (int t = 0; t < 16; ++t) {
            if ((t & 3) > 1) continue;           // owner elements: rt < 8
            const int rt = rtof(t);
            if (w == 0 && t == 0) {
                v2f C0 = a[0];
                float X0 = C0.x + C0.y, XN = C0.x - C0.y;
                v2f H0 = hrow[0];
                v2f HN = ((const v2f*)wsNy)[d];
                v2f Y1 = mk(X0 * H0.x, X0 * H0.y);
                v2f Y2 = mk(XN * HN.x, XN * HN.y);
                v2f S  = mk(Y1.x + Y2.x, Y1.y - Y2.y);
                v2f Dd = mk(Y1.x - Y2.x, Y1.y + Y2.y);
                a[0] = mk(S.x - Dd.y, S.y + Dd.x);
            } else {
                const int cq = (w == 0) ? rev2i(16 - rt) : rev2i(15 - rt);
                const v2f Cq = z[17 * qm + cq];
                const v2f Cp = a[t];
                const v2f cA = mk(0.5f * (Cp.x + Cq.x), 0.5f * (Cp.y - Cq.y));
                const v2f cB = mk(0.5f * (Cp.y + Cq.y), -0.5f * (Cp.x - Cq.x));
                const v2f Wk = cmul(wk0, Ktw(rt));
                const v2f T  = cmul(Wk, cB);
                const v2f X1 = cA + T;
                const v2f X2 = mk(cA.x - T.x, -(cA.y - T.y));  // conj(cA - T)
                const v2f Hp = hrow[(t << 9) + w];
                const v2f Hq = hrow[(cq << 9) + qm];
                const v2f Y1 = cmul(X1, Hp);
                const v2f Y2 = cmul(X2, Hq);
                const v2f S  = mk(Y1.x + Y2.x, Y1.y - Y2.y);
                const v2f Dd = mk(Y1.x - Y2.x, Y1.y + Y2.y);
                const v2f Vk = mk(Wk.x, -Wk.y);
                const v2f U  = cmul(Vk, Dd);
                a[t]            = mk(S.x - U.y, S.y + U.x);     // own Wtil[k]
                z[17 * qm + cq] = mk(S.x + U.y, U.x - S.y);     // partner Wtil
            }
        }
        if (w == 0) {   // self-pair k = 4096 (position 2)
            const v2f Cp = z[2];
            const v2f cA = mk(Cp.x, 0.0f);
            const v2f cB = mk(Cp.y, 0.0f);
            const v2f Wk = mk(0.0f, -1.0f);
            const v2f T  = cmul(Wk, cB);
            const v2f X1 = cA + T;
            const v2f X2 = mk(cA.x - T.x, -(cA.y - T.y));
            const v2f Hp = hrow[(2 << 9)];
            const v2f Y1 = cmul(X1, Hp);
            const v2f Y2 = cmul(X2, Hp);
            const v2f S  = mk(Y1.x + Y2.x, Y1.y - Y2.y);
            const v2f Dd = mk(Y1.x - Y2.x, Y1.y + Y2.y);
            const v2f Vk = mk(0.0f, 1.0f);
            const v2f U  = cmul(Vk, Dd);
            z[2] = mk(S.x - U.y, S.y + U.x);
        }
    }
    __syncthreads();
    // ---- inverse radix-4 (m=1): own 8 from regs, missing 8 from LDS
    {
        const int base = 17 * w;
#pragma unroll
        for (int t = 0; t < 16; ++t)
            if ((t & 3) > 1) a[t] = z[base + t];
        inv4x4(a);
#pragma unroll
        for (int t = 0; t < 16; ++t) z[base + t] = a[t];
    }
    __syncthreads();
    // ---- P5: inverse radix-16, m2 = 4 (t64, conj indices)
    {
        const int j = w & 3, g = w >> 2;
        const int i0 = g * 64 + j;
#pragma unroll
        for (int t = 0; t < 16; ++t) a[t] = z[PHYS(i0 + 4 * t)];
        bfly16<4, 63, true>(a, t64, j);
#pragma unroll
        for (int t = 0; t < 16; ++t) z[PHYS(i0 + 4 * t)] = a[t];
    }
    __syncthreads();
    // ---- P6: inverse radix-16, m2 = 64 (tab1k, conj indices)
    {
        const int j = w & 63, blk = w >> 6;
        const int base = PHYS(blk * 1024 + j);
#pragma unroll
        for (int t = 0; t < 16; ++t) a[t] = z[base + 68 * t];
        bfly16<64, 1023, true>(a, tb, j);
#pragma unroll
        for (int t = 0; t < 16; ++t) z[base + 68 * t] = a[t];
    }
    __syncthreads();
    // ---- P7: inverse radix-4(m=1024) + inverse radix-2(m=4096), store y
    {
        v2f* yr = (v2f*)yg + (size_t)(b * DCH + d) * 4096;
#pragma unroll
        for (int g = 0; g < 2; ++g) {
            const int i0 = w + 512 * g;
            const int pb = PHYS(i0);
            v2f q0 = z[pb],            q1 = z[pb + 1088],
                q2 = z[pb + 2 * 1088], q3 = z[pb + 3 * 1088],
                q4 = z[pb + 4 * 1088], q5 = z[pb + 5 * 1088],
                q6 = z[pb + 6 * 1088], q7 = z[pb + 7 * 1088];
            const v2f vA  = wtw((float)i0 * (1.0f / 8192.0f));
            const v2f vB  = cmul(vA, vA);
            const v2f vB2 = cmul(vB, vB);
            const v2f vB3 = cmul(vB2, vB);
            v2f b1 = cmul(q1, vB), b2 = cmul(q2, vB2), b3 = cmul(q3, vB3);
            v2f t0 = q0 + b2, t1 = q0 - b2, t2 = b1 + b3;
            v2f dd = b3 - b1;
            v2f t3 = mnegi(dd);
            v2f T0 = t0 + t2, T1 = t1 + t3, T2 = t0 - t2, T3 = t1 - t3;
            b1 = cmul(q5, vB); b2 = cmul(q6, vB2); b3 = cmul(q7, vB3);
            t0 = q4 + b2; t1 = q4 - b2; t2 = b1 + b3;
            dd = b3 - b1;
            t3 = mnegi(dd);
            v2f B0 = t0 + t2, B1 = t1 + t3, B2 = t0 - t2, B3 = t1 - t3;
            yr[i0]        = T0 + cmul(B0, vA);
            yr[i0 + 1024] = T1 + cmul(B1, cmul(vA, mk(R2, R2)));
            yr[i0 + 2048] = T2 + cmul(B2, mk(-vA.y, vA.x));   // i*vA
            yr[i0 + 3072] = T3 + cmul(B3, cmul(vA, mk(-R2, R2)));
        }
    }
}

// ===================== fallback: verified round-5 16K-FFT single-kernel path =====================
__device__ __forceinline__ int drev14(int v) {
    int r = 0;
#pragma unroll
    for (int i = 0; i < 7; ++i) { r = (r << 2) | (v & 3); v >>= 2; }
    return r;
}
__device__ __forceinline__ int drev10(int v) {
    int r = 0;
#pragma unroll
    for (int i = 0; i < 5; ++i) { r = (r << 2) | (v & 3); v >>= 2; }
    return r;
}
__device__ __forceinline__ void dif16(v2f* a, float r1) {
    const v2f w10 = wtw(r1);
    const v2f sq  = cmul(w10, w10);
    const v2f cu  = cmul(sq, w10);
#pragma unroll
    for (int ai = 0; ai < 4; ++ai) {
        v2f w1, w2, w3;
        if (ai == 0)      { w1 = w10; w2 = sq; w3 = cu; }
        else if (ai == 1) { w1 = cmul(w10, mk(C1F, -S1F));
                            w2 = cmul(sq,  mk(C2F, -C2F));
                            w3 = cmul(cu,  mk(S1F, -C1F)); }
        else if (ai == 2) { w1 = cmul(w10, mk(C2F, -C2F));
                            w2 = mk(sq.y, -sq.x);
                            w3 = cmul(cu,  mk(-C2F, -C2F)); }
        else              { w1 = cmul(w10, mk(S1F, -C1F));
                            w2 = cmul(sq,  mk(-C2F, -C2F));
                            w3 = cmul(cu,  mk(-C1F,  S1F)); }
        v2f u0 = a[ai], u1 = a[ai + 4], u2 = a[ai + 8], u3 = a[ai + 12];
        v2f t0 = u0 + u2, t1 = u1 + u3;
        v2f t2 = u0 - u2, t3 = u1 - u3;
        v2f mi3 = mnegi(t3);
        a[ai]      = t0 + t1;
        a[ai + 4]  = cmul(t2 + mi3, w1);
        a[ai + 8]  = cmul(t0 - t1, w2);
        a[ai + 12] = cmul(t2 - mi3, w3);
    }
    const v2f v1 = cmul(sq, sq);
    const v2f v2 = cmul(v1, v1);
    const v2f v3 = cmul(v2, v1);
#pragma unroll
    for (int p = 0; p < 4; ++p) {
        v2f u0 = a[4 * p], u1 = a[4 * p + 1], u2 = a[4 * p + 2], u3 = a[4 * p + 3];
        v2f t0 = u0 + u2, t1 = u1 + u3;
        v2f t2 = u0 - u2, t3 = u1 - u3;
        v2f mi3 = mnegi(t3);
        a[4 * p]     = t0 + t1;
        a[4 * p + 1] = cmul(t2 + mi3, v1);
        a[4 * p + 2] = cmul(t0 - t1, v2);
        a[4 * p + 3] = cmul(t2 - mi3, v3);
    }
}
__device__ __forceinline__ void dit16(v2f* a, float r1) {
    const v2f w10 = wtw(r1);
    const v2f sq  = cmul(w10, w10);
    const v2f cu  = cmul(sq, w10);
    const v2f v1  = cmul(sq, sq);
    const v2f v2  = cmul(v1, v1);
    const v2f v3  = cmul(v2, v1);
#pragma unroll
    for (int p = 0; p < 4; ++p) {
        v2f b0 = a[4 * p];
        v2f b1 = cmul(a[4 * p + 1], v1);
        v2f b2 = cmul(a[4 * p + 2], v2);
        v2f b3 = cmul(a[4 * p + 3], v3);
        v2f t0 = b0 + b2, t1 = b0 - b2;
        v2f t2 = b1 + b3;
        v2f dd = b3 - b1;
        v2f t3 = mnegi(dd);
        a[4 * p]     = t0 + t2;
        a[4 * p + 1] = t1 + t3;
        a[4 * p + 2] = t0 - t2;
        a[4 * p + 3] = t1 - t3;
    }
#pragma unroll
    for (int ai = 0; ai < 4; ++ai) {
        v2f w1, w2, w3;
        if (ai == 0)      { w1 = w10; w2 = sq; w3 = cu; }
        else if (ai == 1) { w1 = cmul(w10, mk(C1F, S1F));
                            w2 = cmul(sq,  mk(C2F, C2F));
                            w3 = cmul(cu,  mk(S1F, C1F)); }
        else if (ai == 2) { w1 = cmul(w10, mk(C2F, C2F));
                            w2 = mk(-sq.y, sq.x);
                            w3 = cmul(cu,  mk(-C2F, C2F)); }
        else              { w1 = cmul(w10, mk(S1F, C1F));
                            w2 = cmul(sq,  mk(-C2F, C2F));
                            w3 = cmul(cu,  mk(-C1F, -S1F)); }
        v2f b0 = a[ai];
        v2f b1 = cmul(a[ai + 4], w1);
        v2f b2 = cmul(a[ai + 8], w2);
        v2f b3 = cmul(a[ai + 12], w3);
        v2f t0 = b0 + b2, t1 = b0 - b2;
        v2f t2 = b1 + b3;
        v2f dd = b3 - b1;
        v2f t3 = mnegi(dd);
        a[ai]      = t0 + t2;
        a[ai + 4]  = t1 + t3;
        a[ai + 8]  = t0 - t2;
        a[ai + 12] = t1 - t3;
    }
}

extern "C" __global__ void __launch_bounds__(NTH2, 4)
fftconv_v2(const float* __restrict__ hg, const float* __restrict__ xg,
           const float* __restrict__ bg, float* __restrict__ yg) {
    extern __shared__ v2f z[];
    const int w = threadIdx.x;
    const int bid = blockIdx.x;
    const int d = bid >> 2, b = bid & 3;
    const float* xr = xg + (size_t)(b * DCH + d) * 8192;
    const float* hr = hg + (size_t)d * 8192;
    v2f a[16];
    float xv[8];
    {
#pragma unroll
        for (int t = 0; t < 8; ++t) {
            xv[t] = xr[w + 1024 * t];
            float hv = hr[w + 1024 * t];
            a[t] = mk(xv[t], hv);
        }
        const float r1 = -(float)w * (1.0f / 16384.0f);
#pragma unroll
        for (int ai = 0; ai < 4; ++ai) {
            v2f u0 = a[ai], u1 = a[ai + 4];
            v2f mi3 = mk(u1.y, -u1.x);
            v2f w1 = wtw(r1 - 0.0625f * ai);
            v2f w2 = cmul(w1, w1), w3 = cmul(w2, w1);
            a[ai]      = u0 + u1;
            a[ai + 4]  = cmul(u0 + mi3, w1);
            a[ai + 8]  = cmul(u0 - u1, w2);
            a[ai + 12] = cmul(u0 - mi3, w3);
        }
        v2f v1 = wtw(4.0f * r1);
        v2f v2 = cmul(v1, v1), v3 = cmul(v2, v1);
#pragma unroll
        for (int p = 0; p < 4; ++p) {
            v2f u0 = a[4 * p], u1 = a[4 * p + 1], u2 = a[4 * p + 2], u3 = a[4 * p + 3];
            v2f t0 = u0 + u2, t1 = u1 + u3;
            v2f t2 = u0 - u2, t3 = u1 - u3;
            v2f mi3 = mnegi(t3);
            a[4 * p]     = t0 + t1;
            a[4 * p + 1] = cmul(t2 + mi3, v1);
            a[4 * p + 2] = cmul(t0 - t1, v2);
            a[4 * p + 3] = cmul(t2 - mi3, v3);
        }
        const int base = PHYS(w);
#pragma unroll
        for (int t = 0; t < 16; ++t) z[base + 1088 * t] = a[t];
    }
    __syncthreads();
    {
        const int j = w & 63, grp = w >> 6;
        const int base = PHYS(grp * 1024 + j);
#pragma unroll
        for (int t = 0; t < 16; ++t) a[t] = z[base + 68 * t];
        dif16(a, -(float)j * (1.0f / 1024.0f));
#pragma unroll
        for (int t = 0; t < 16; ++t) z[base + 68 * t] = a[t];
    }
    __syncthreads();
    {
        const int j = w & 3, grp = w >> 2;
        const int i0 = grp * 64 + j;
#pragma unroll
        for (int t = 0; t < 16; ++t) a[t] = z[PHYS(i0 + 4 * t)];
        dif16(a, -(float)j * (1.0f / 64.0f));
#pragma unroll
        for (int t = 0; t < 16; ++t) z[PHYS(i0 + 4 * t)] = a[t];
    }
    __syncthreads();
    {
        const int base = 17 * w;
#pragma unroll
        for (int t = 0; t < 16; ++t) a[t] = z[base + t];
        fwd4x4(a);
#pragma unroll
        for (int t = 0; t < 16; ++t) z[base + t] = a[t];
        __syncthreads();
        const int kw = drev10(w);
#pragma unroll
        for (int t = 0; t < 16; ++t) {
            const int rt = (((t & 3) << 2) | (t >> 2));
            const int k = (rt << 10) | kw;
            const int pp = drev14(16384 - k);
            const v2f Zm = z[PHYS(pp)];
            const v2f Zp = a[t];
            const v2f A  = mk(Zp.x + Zm.x, Zp.y - Zm.y);
            const v2f Dv = mk(Zp.x - Zm.x, Zp.y + Zm.y);
            const v2f X  = mk(0.5f * A.x, 0.5f * A.y);
            const v2f H  = mk(0.5f * Dv.y, -0.5f * Dv.x);
            a[t] = cmul(X, H);
        }
        __syncthreads();
        inv4x4(a);
#pragma unroll
        for (int t = 0; t < 16; ++t) z[base + t] = a[t];
    }
    __syncthreads();
    {
        const int j = w & 3, grp = w >> 2;
        const int i0 = grp * 64 + j;
#pragma unroll
        for (int t = 0; t < 16; ++t) a[t] = z[PHYS(i0 + 4 * t)];
        dit16(a, (float)j * (1.0f / 64.0f));
#pragma unroll
        for (int t = 0; t < 16; ++t) z[PHYS(i0 + 4 * t)] = a[t];
    }
    __syncthreads();
    {
        const int j = w & 63, grp = w >> 6;
        const int base = PHYS(grp * 1024 + j);
#pragma unroll
        for (int t = 0; t < 16; ++t) a[t] = z[base + 68 * t];
        dit16(a, (float)j * (1.0f / 1024.0f));
#pragma unroll
        for (int t = 0; t < 16; ++t) z[base + 68 * t] = a[t];
    }
    __syncthreads();
    {
        const int base = PHYS(w);
#pragma unroll
        for (int t = 0; t < 16; ++t) a[t] = z[base + 1088 * t];
        const float r1 = (float)w * (1.0f / 16384.0f);
        v2f v1 = wtw(4.0f * r1);
        v2f v2 = cmul(v1, v1), v3 = cmul(v2, v1);
#pragma unroll
        for (int p = 0; p < 4; ++p) {
            v2f b0 = a[4 * p];
            v2f b1 = cmul(a[4 * p + 1], v1);
            v2f b2 = cmul(a[4 * p + 2], v2);
            v2f b3 = cmul(a[4 * p + 3], v3);
            v2f t0 = b0 + b2, t1 = b0 - b2;
            v2f t2 = b1 + b3;
            v2f dd = b3 - b1;
            v2f t3 = mnegi(dd);
            a[4 * p]     = t0 + t2;
            a[4 * p + 1] = t1 + t3;
            a[4 * p + 2] = t0 - t2;
            a[4 * p + 3] = t1 - t3;
        }
        const float bd = bg[d];
        const float invN = 1.0f / 16384.0f;
#pragma unroll
        for (int ai = 0; ai < 4; ++ai) {
            v2f w1 = wtw(r1 + 0.0625f * ai);
            v2f w2 = cmul(w1, w1), w3 = cmul(w2, w1);
            v2f b0 = a[ai];
            v2f vv1 = cmul(a[ai + 4], w1);
            v2f vv2 = cmul(a[ai + 8], w2);
            v2f vv3 = cmul(a[ai + 12], w3);
            v2f t0 = b0 + vv2, t1 = b0 - vv2;
            v2f t2 = vv1 + vv3;
            v2f dd = vv3 - vv1;
            v2f t3 = mnegi(dd);
            v2f o0 = t0 + t2;
            v2f o1 = t1 + t3;
            yg[(size_t)(b * DCH + d) * 8192 + w + 1024 * ai]        = fmaf(xv[ai], bd, o0.x * invN);
            yg[(size_t)(b * DCH + d) * 8192 + w + 4096 + 1024 * ai] = fmaf(xv[ai + 4], bd, o1.x * invN);
        }
    }
}

extern "C" void kernel_launch(void* const* d_in, const int* in_sizes, int n_in,
                              void* d_out, int out_size, void* d_ws, size_t ws_size,
                              hipStream_t stream) {
    (void)in_sizes; (void)n_in; (void)out_size;
    const float* h = (const float*)d_in[0];
    const float* x = (const float*)d_in[1];
    const float* B = (const float*)d_in[2];
    float* y = (float*)d_out;

    const size_t need = (size_t)(DCH * NHALF + DCH) * sizeof(float2);
    if (ws_size >= need && d_ws != nullptr) {
        (void)hipFuncSetAttribute((const void*)hspec_kernel,
                                  hipFuncAttributeMaxDynamicSharedMemorySize,
                                  LDSE * (int)sizeof(float2));
        (void)hipFuncSetAttribute((const void*)fftconv_main,
                                  hipFuncAttributeMaxDynamicSharedMemorySize,
                                  LDSE * (int)sizeof(float2));
        float* wsHf = (float*)d_ws;
        float* wsNy = wsHf + 2 * (size_t)DCH * NHALF;
        hspec_kernel<<<dim3(DCH), dim3(NTH), LDSE * sizeof(float2), stream>>>(h, B, wsHf, wsNy);
        fftconv_main<<<dim3(4 * DCH), dim3(NTH), LDSE * sizeof(float2), stream>>>(x, wsHf, wsNy, y);
    } else {
        (void)hipFuncSetAttribute((const void*)fftconv_v2,
                                  hipFuncAttributeMaxDynamicSharedMemorySize,
                                  LDSE2 * (int)sizeof(float2));
        fftconv_v2<<<dim3(4 * DCH), dim3(NTH2), LDSE2 * sizeof(float2), stream>>>(h, x, B, y);
    }
}

// Round 8
// 134.664 us; speedup vs baseline: 1.0523x; 1.0523x over previous
//
#include <hip/hip_runtime.h>

#define DCH   768
#define NHALF 8192
#define NTH   512
#define PHYS(i) ((i) + ((i) >> 4))
#define LDSE  (NHALF + NHALF / 16)     // 8704 v2f = 69632 B
#define NFULL 16384
#define NTH2  1024
#define LDSE2 (NFULL + NFULL / 16)     // fallback: 17408 v2f

#define C1F 0.9238795325112867f        // cos(pi/8)
#define S1F 0.3826834323650898f        // sin(pi/8)
#define C2F 0.7071067811865476f        // cos(pi/4)

typedef float v2f __attribute__((ext_vector_type(2)));

__device__ __forceinline__ v2f mk(float x, float y) { v2f r; r.x = x; r.y = y; return r; }
__device__ __forceinline__ v2f cmul(v2f a, v2f b) {
    v2f re = a.xx * b;                       // {ax*bx, ax*by}
    return __builtin_elementwise_fma(mk(-a.y, a.y), mk(b.y, b.x), re);
}
__device__ __forceinline__ v2f mnegi(v2f t) { return mk(t.y, -t.x); }   // -i*t
__device__ __forceinline__ v2f wtw(float rev) {   // e^{2*pi*i*rev}
    return mk(__builtin_amdgcn_cosf(rev), __builtin_amdgcn_sinf(rev));
}
__device__ __forceinline__ int drev8(int v) {        // 4-digit base-4 reversal of 8-bit
    return ((v & 3) << 6) | ((v & 12) << 2) | ((v >> 2) & 12) | ((v >> 6) & 3);
}
__device__ __forceinline__ constexpr int rev2i(int a) { return ((a & 3) << 2) | ((a >> 2) & 3); }
__device__ __forceinline__ constexpr int rtof(int t)  { return ((t & 3) << 2) | (t >> 2); }

__device__ __forceinline__ v2f Ktw(int rt) {      // e^{-2*pi*i*rt/32}
    const float KC[16] = {1.0f, 0.980785280f, 0.923879533f, 0.831469612f,
                          0.707106781f, 0.555570233f, 0.382683432f, 0.195090322f,
                          0.0f, -0.195090322f, -0.382683432f, -0.555570233f,
                          -0.707106781f, -0.831469612f, -0.923879533f, -0.980785280f};
    const float KS[16] = {0.0f, -0.195090322f, -0.382683432f, -0.555570233f,
                          -0.707106781f, -0.831469612f, -0.923879533f, -0.980785280f,
                          -1.0f, -0.980785280f, -0.923879533f, -0.831469612f,
                          -0.707106781f, -0.555570233f, -0.382683432f, -0.195090322f};
    return mk(KC[rt], KS[rt]);
}

// -------- fused radix-16 DIF (levels m1=4*m2 then m2); r1 = -j/(16*m2)
__device__ __forceinline__ void dif16(v2f* a, float r1) {
    const v2f w10 = wtw(r1);
    const v2f sq  = cmul(w10, w10);
    const v2f cu  = cmul(sq, w10);
#pragma unroll
    for (int ai = 0; ai < 4; ++ai) {
        v2f w1, w2, w3;
        if (ai == 0)      { w1 = w10; w2 = sq; w3 = cu; }
        else if (ai == 1) { w1 = cmul(w10, mk(C1F, -S1F));
                            w2 = cmul(sq,  mk(C2F, -C2F));
                            w3 = cmul(cu,  mk(S1F, -C1F)); }
        else if (ai == 2) { w1 = cmul(w10, mk(C2F, -C2F));
                            w2 = mk(sq.y, -sq.x);           // sq * (-i)
                            w3 = cmul(cu,  mk(-C2F, -C2F)); }
        else              { w1 = cmul(w10, mk(S1F, -C1F));
                            w2 = cmul(sq,  mk(-C2F, -C2F));
                            w3 = cmul(cu,  mk(-C1F,  S1F)); }
        v2f u0 = a[ai], u1 = a[ai + 4], u2 = a[ai + 8], u3 = a[ai + 12];
        v2f t0 = u0 + u2, t1 = u1 + u3;
        v2f t2 = u0 - u2, t3 = u1 - u3;
        v2f mi3 = mnegi(t3);
        a[ai]      = t0 + t1;
        a[ai + 4]  = cmul(t2 + mi3, w1);
        a[ai + 8]  = cmul(t0 - t1, w2);
        a[ai + 12] = cmul(t2 - mi3, w3);
    }
    const v2f v1 = cmul(sq, sq);                  // w10^4
    const v2f v2 = cmul(v1, v1);
    const v2f v3 = cmul(v2, v1);
#pragma unroll
    for (int p = 0; p < 4; ++p) {
        v2f u0 = a[4 * p], u1 = a[4 * p + 1], u2 = a[4 * p + 2], u3 = a[4 * p + 3];
        v2f t0 = u0 + u2, t1 = u1 + u3;
        v2f t2 = u0 - u2, t3 = u1 - u3;
        v2f mi3 = mnegi(t3);
        a[4 * p]     = t0 + t1;
        a[4 * p + 1] = cmul(t2 + mi3, v1);
        a[4 * p + 2] = cmul(t0 - t1, v2);
        a[4 * p + 3] = cmul(t2 - mi3, v3);
    }
}
// -------- fused inverse radix-16 (levels m2 then m1=4*m2); r1 = +j/(16*m2)
__device__ __forceinline__ void dit16(v2f* a, float r1) {
    const v2f w10 = wtw(r1);
    const v2f sq  = cmul(w10, w10);
    const v2f cu  = cmul(sq, w10);
    const v2f v1  = cmul(sq, sq);
    const v2f v2  = cmul(v1, v1);
    const v2f v3  = cmul(v2, v1);
#pragma unroll
    for (int p = 0; p < 4; ++p) {
        v2f b0 = a[4 * p];
        v2f b1 = cmul(a[4 * p + 1], v1);
        v2f b2 = cmul(a[4 * p + 2], v2);
        v2f b3 = cmul(a[4 * p + 3], v3);
        v2f t0 = b0 + b2, t1 = b0 - b2;
        v2f t2 = b1 + b3;
        v2f dd = b3 - b1;
        v2f t3 = mnegi(dd);
        a[4 * p]     = t0 + t2;
        a[4 * p + 1] = t1 + t3;
        a[4 * p + 2] = t0 - t2;
        a[4 * p + 3] = t1 - t3;
    }
#pragma unroll
    for (int ai = 0; ai < 4; ++ai) {
        v2f w1, w2, w3;
        if (ai == 0)      { w1 = w10; w2 = sq; w3 = cu; }
        else if (ai == 1) { w1 = cmul(w10, mk(C1F, S1F));
                            w2 = cmul(sq,  mk(C2F, C2F));
                            w3 = cmul(cu,  mk(S1F, C1F)); }
        else if (ai == 2) { w1 = cmul(w10, mk(C2F, C2F));
                            w2 = mk(-sq.y, sq.x);           // sq * (+i)
                            w3 = cmul(cu,  mk(-C2F, C2F)); }
        else              { w1 = cmul(w10, mk(S1F, C1F));
                            w2 = cmul(sq,  mk(-C2F, C2F));
                            w3 = cmul(cu,  mk(-C1F, -S1F)); }
        v2f b0 = a[ai];
        v2f b1 = cmul(a[ai + 4], w1);
        v2f b2 = cmul(a[ai + 8], w2);
        v2f b3 = cmul(a[ai + 12], w3);
        v2f t0 = b0 + b2, t1 = b0 - b2;
        v2f t2 = b1 + b3;
        v2f dd = b3 - b1;
        v2f t3 = mnegi(dd);
        a[ai]      = t0 + t2;
        a[ai + 4]  = t1 + t3;
        a[ai + 8]  = t0 - t2;
        a[ai + 12] = t1 - t3;
    }
}
__device__ __forceinline__ void fwd4x4(v2f* a) {   // radix-4 DIF, m=1, twiddle-free
#pragma unroll
    for (int u = 0; u < 4; ++u) {
        v2f u0 = a[4*u], u1 = a[4*u+1], u2 = a[4*u+2], u3 = a[4*u+3];
        v2f t0 = u0 + u2, t1 = u1 + u3, t2 = u0 - u2, t3 = u1 - u3;
        v2f mi3 = mnegi(t3);
        a[4*u] = t0 + t1; a[4*u+1] = t2 + mi3;
        a[4*u+2] = t0 - t1; a[4*u+3] = t2 - mi3;
    }
}
__device__ __forceinline__ void inv4x4(v2f* a) {   // inverse radix-4, m=1
#pragma unroll
    for (int u = 0; u < 4; ++u) {
        v2f b0 = a[4*u], b1 = a[4*u+1], b2 = a[4*u+2], b3 = a[4*u+3];
        v2f t0 = b0 + b2, t1 = b0 - b2, t2 = b1 + b3;
        v2f dd = b3 - b1;
        v2f t3 = mnegi(dd);
        a[4*u] = t0 + t2; a[4*u+1] = t1 + t3;
        a[4*u+2] = t0 - t2; a[4*u+3] = t1 - t3;
    }
}

// Forward 8192-pt complex FFT; input preloaded in c[8] (c[4g+t] = src[w+512g+1024t]).
// PUB8: in P4a publish only the 8 non-owner slots ((t&3)>1) — enough for the
// main kernel's pair-combine; hspec needs the full publish.
template<bool PUB8>
__device__ __forceinline__ void fwd8k_body(const v2f* __restrict__ c,
                                           v2f* __restrict__ z, const int w, v2f* a) {
    const float R2 = 0.70710678118654752f;
    const v2f wA0 = wtw(-(float)w * (1.0f / 8192.0f));
    // ---- P1: radix-2(m=4096, top half zero) + radix-4(m=1024)
#pragma unroll
    for (int g = 0; g < 2; ++g) {
        const int i0 = w + 512 * g;
        v2f c0 = c[4*g], c1 = c[4*g+1], c2 = c[4*g+2], c3 = c[4*g+3];
        const v2f wA  = (g == 0) ? wA0 : cmul(wA0, mk(C1F, -S1F));  // rotate by e^{-i*pi/8}
        const v2f wB  = cmul(wA, wA);
        const v2f wB2 = cmul(wB, wB);
        const v2f wB3 = cmul(wB2, wB);
        const int pb = PHYS(i0);
        v2f t0 = c0 + c2, t1 = c1 + c3, t2 = c0 - c2, t3 = c1 - c3;
        v2f mi3 = mnegi(t3);
        z[pb]            = t0 + t1;
        z[pb + 1088]     = cmul(t2 + mi3, wB);
        z[pb + 2 * 1088] = cmul(t0 - t1, wB2);
        z[pb + 3 * 1088] = cmul(t2 - mi3, wB3);
        v2f d0 = cmul(c0, wA);
        v2f d1 = cmul(c1, cmul(wA, mk(R2, -R2)));
        v2f d2 = cmul(c2, mk(wA.y, -wA.x));           // -i*wA
        v2f d3 = cmul(c3, cmul(wA, mk(-R2, -R2)));
        t0 = d0 + d2; t1 = d1 + d3; t2 = d0 - d2; t3 = d1 - d3;
        mi3 = mnegi(t3);
        z[pb + 4 * 1088] = t0 + t1;
        z[pb + 5 * 1088] = cmul(t2 + mi3, wB);
        z[pb + 6 * 1088] = cmul(t0 - t1, wB2);
        z[pb + 7 * 1088] = cmul(t2 - mi3, wB3);
    }
    __syncthreads();
    // ---- P2: radix-16, m2 = 64
    {
        const int j = w & 63, blk = w >> 6;
        const int base = PHYS(blk * 1024 + j);
#pragma unroll
        for (int t = 0; t < 16; ++t) a[t] = z[base + 68 * t];
        dif16(a, -(float)j * (1.0f / 1024.0f));
#pragma unroll
        for (int t = 0; t < 16; ++t) z[base + 68 * t] = a[t];
    }
    __syncthreads();
    // ---- P3: radix-16, m2 = 4
    {
        const int j = w & 3, g = w >> 2;
        const int i0 = g * 64 + j;
#pragma unroll
        for (int t = 0; t < 16; ++t) a[t] = z[PHYS(i0 + 4 * t)];
        dif16(a, -(float)j * (1.0f / 64.0f));
#pragma unroll
        for (int t = 0; t < 16; ++t) z[PHYS(i0 + 4 * t)] = a[t];
    }
    __syncthreads();
    // ---- P4a: final radix-4 (m=1) in regs, publish C
    {
        const int base = 17 * w;
#pragma unroll
        for (int t = 0; t < 16; ++t) a[t] = z[base + t];
        fwd4x4(a);
#pragma unroll
        for (int t = 0; t < 16; ++t)
            if (!PUB8 || (t & 3) > 1) z[base + t] = a[t];
    }
    __syncthreads();
}

// ============ kernel 1: per-channel H spectrum, scaled by 1/N, H += B
extern "C" __global__ void __launch_bounds__(NTH, 4)
hspec_kernel(const float* __restrict__ hg, const float* __restrict__ bg,
             float* __restrict__ wsHf, float* __restrict__ wsNy) {
    extern __shared__ v2f z[];
    const int w = threadIdx.x;
    const int d = blockIdx.x;
    const v2f* hr = (const v2f*)hg + (size_t)d * 4096;
    v2f a[16], c[8];
#pragma unroll
    for (int g = 0; g < 2; ++g)
#pragma unroll
        for (int t = 0; t < 4; ++t) c[4*g + t] = hr[w + 512*g + 1024*t];
    fwd8k_body<false>(c, z, w, a);

    const float Bd = bg[d];
    const float invN = 1.0f / 16384.0f;
    v2f* out = (v2f*)wsHf + (size_t)d * NHALF;
    const int wm = w & 255, whi = w >> 8;
    const int k0 = 2 * drev8(wm) + whi;
    const v2f wk0 = wtw(-(float)k0 * (1.0f / 16384.0f));
    int qm = 0;
    if (w != 0) { const int bq = (512 - k0) >> 1; qm = (whi << 8) | drev8(bq); }
#pragma unroll
    for (int t = 0; t < 16; ++t) {
        const int rt = rtof(t);
        if (w == 0 && t == 0) {
            v2f C0 = a[0];
            out[0] = mk((C0.x + C0.y + Bd) * invN, 0.0f);
            ((v2f*)wsNy)[d] = mk((C0.x - C0.y + Bd) * invN, 0.0f);
        } else {
            const int cq = (w == 0) ? rev2i(16 - rt) : rev2i(15 - rt);
            const v2f Cq = z[17 * qm + cq];
            const v2f Cp = a[t];
            const v2f cA = mk(0.5f * (Cp.x + Cq.x), 0.5f * (Cp.y - Cq.y));
            const v2f cB = mk(0.5f * (Cp.y + Cq.y), -0.5f * (Cp.x - Cq.x));
            const v2f Wk = cmul(wk0, Ktw(rt));
            const v2f Hf = cA + cmul(Wk, cB);
            out[(t << 9) + w] = mk((Hf.x + Bd) * invN, Hf.y * invN);
        }
    }
}

// ============ kernel 2: main conv
extern "C" __global__ void __launch_bounds__(NTH, 4)
fftconv_main(const float* __restrict__ xg, const float* __restrict__ wsHf,
             const float* __restrict__ wsNy, float* __restrict__ yg) {
    extern __shared__ v2f z[];
    const int w = threadIdx.x;
    const int bid = blockIdx.x;
    const int d = bid >> 2, b = bid & 3;
    const v2f* xr = (const v2f*)xg + (size_t)(b * DCH + d) * 4096;
    const v2f* hrow = (const v2f*)wsHf + (size_t)d * NHALF;
    const float R2 = 0.70710678118654752f;
    v2f a[16], c[8];

    // ---- x loads FIRST (vmcnt retires in order: H gathers must not gate P1)
#pragma unroll
    for (int g = 0; g < 2; ++g)
#pragma unroll
        for (int t = 0; t < 4; ++t) c[4*g + t] = xr[w + 512*g + 1024*t];

    // ---- prefetch H-spectrum operands for P4b (latency hides under P1..P4a)
    const int wm = w & 255, whi = w >> 8;
    const int k0 = 2 * drev8(wm) + whi;
    int qm = 0;
    if (w != 0) { const int bq = (512 - k0) >> 1; qm = (whi << 8) | drev8(bq); }
    v2f hp[8], hq[8];
#pragma unroll
    for (int u = 0; u < 8; ++u) {
        const int t = ((u >> 1) << 2) | (u & 1);      // owner t: 0,1,4,5,8,9,12,13
        const int rt = rtof(t);
        const int cq = (w == 0) ? rev2i(16 - rt) : rev2i(15 - rt);
        hp[u] = hrow[(t << 9) + w];
        hq[u] = hrow[(cq << 9) + qm];
    }
    v2f hn = ((const v2f*)wsNy)[d];
    // keep-alive: pin prefetched values so the compiler doesn't sink the loads
    asm volatile("" :: "v"(hp[0]), "v"(hp[1]), "v"(hp[2]), "v"(hp[3]),
                       "v"(hp[4]), "v"(hp[5]), "v"(hp[6]), "v"(hp[7]));
    asm volatile("" :: "v"(hq[0]), "v"(hq[1]), "v"(hq[2]), "v"(hq[3]),
                       "v"(hq[4]), "v"(hq[5]), "v"(hq[6]), "v"(hq[7]), "v"(hn));

    fwd8k_body<true>(c, z, w, a);

    // ---- P4b: pair-owner combine; owner Wtil stays in regs, partner to LDS
    {
        const v2f wk0 = wtw(-(float)k0 * (1.0f / 16384.0f));
        int u = 0;
#pragma unroll
        for (int t = 0; t < 16; ++t) {
            if ((t & 3) > 1) continue;           // owner elements: rt < 8
            const int rt = rtof(t);
            if (w == 0 && t == 0) {
                v2f C0 = a[0];
                float X0 = C0.x + C0.y, XN = C0.x - C0.y;
                v2f Y1 = mk(X0 * hp[0].x, X0 * hp[0].y);
                v2f Y2 = mk(XN * hn.x, XN * hn.y);
                v2f S  = mk(Y1.x + Y2.x, Y1.y - Y2.y);
                v2f Dd = mk(Y1.x - Y2.x, Y1.y + Y2.y);
                a[0] = mk(S.x - Dd.y, S.y + Dd.x);
            } else {
                const int cq = (w == 0) ? rev2i(16 - rt) : rev2i(15 - rt);
                const v2f Cq = z[17 * qm + cq];
                const v2f Cp = a[t];
                const v2f cA = mk(0.5f * (Cp.x + Cq.x), 0.5f * (Cp.y - Cq.y));
                const v2f cB = mk(0.5f * (Cp.y + Cq.y), -0.5f * (Cp.x - Cq.x));
                const v2f Wk = cmul(wk0, Ktw(rt));
                const v2f T  = cmul(Wk, cB);
                const v2f X1 = cA + T;
                const v2f X2 = mk(cA.x - T.x, -(cA.y - T.y));  // conj(cA - T)
                const v2f Y1 = cmul(X1, hp[u]);
                const v2f Y2 = cmul(X2, hq[u]);
                const v2f S  = mk(Y1.x + Y2.x, Y1.y - Y2.y);
                const v2f Dd = mk(Y1.x - Y2.x, Y1.y + Y2.y);
                const v2f Vk = mk(Wk.x, -Wk.y);
                const v2f U  = cmul(Vk, Dd);
                a[t]            = mk(S.x - U.y, S.y + U.x);     // own Wtil[k]
                z[17 * qm + cq] = mk(S.x + U.y, U.x - S.y);     // partner Wtil
            }
            ++u;
        }
        if (w == 0) {   // self-pair k = 4096 (position 2)
            const v2f Cp = z[2];
            const v2f cA = mk(Cp.x, 0.0f);
            const v2f cB = mk(Cp.y, 0.0f);
            const v2f Wk = mk(0.0f, -1.0f);
            const v2f T  = cmul(Wk, cB);
            const v2f X1 = cA + T;
            const v2f X2 = mk(cA.x - T.x, -(cA.y - T.y));
            const v2f Hp = hrow[(2 << 9)];
            const v2f Y1 = cmul(X1, Hp);
            const v2f Y2 = cmul(X2, Hp);
            const v2f S  = mk(Y1.x + Y2.x, Y1.y - Y2.y);
            const v2f Dd = mk(Y1.x - Y2.x, Y1.y + Y2.y);
            const v2f Vk = mk(0.0f, 1.0f);
            const v2f U  = cmul(Vk, Dd);
            z[2] = mk(S.x - U.y, S.y + U.x);
        }
    }
    __syncthreads();
    // ---- inverse radix-4 (m=1): own 8 from regs, missing 8 from LDS
    {
        const int base = 17 * w;
#pragma unroll
        for (int t = 0; t < 16; ++t)
            if ((t & 3) > 1) a[t] = z[base + t];
        inv4x4(a);
#pragma unroll
        for (int t = 0; t < 16; ++t) z[base + t] = a[t];
    }
    __syncthreads();
    // ---- P5: inverse radix-16, m2 = 4
    {
        const int j = w & 3, g = w >> 2;
        const int i0 = g * 64 + j;
#pragma unroll
        for (int t = 0; t < 16; ++t) a[t] = z[PHYS(i0 + 4 * t)];
        dit16(a, (float)j * (1.0f / 64.0f));
#pragma unroll
        for (int t = 0; t < 16; ++t) z[PHYS(i0 + 4 * t)] = a[t];
    }
    __syncthreads();
    // ---- P6: inverse radix-16, m2 = 64
    {
        const int j = w & 63, blk = w >> 6;
        const int base = PHYS(blk * 1024 + j);
#pragma unroll
        for (int t = 0; t < 16; ++t) a[t] = z[base + 68 * t];
        dit16(a, (float)j * (1.0f / 1024.0f));
#pragma unroll
        for (int t = 0; t < 16; ++t) z[base + 68 * t] = a[t];
    }
    __syncthreads();
    // ---- P7: inverse radix-4(m=1024) + inverse radix-2(m=4096), store y
    {
        v2f* yr = (v2f*)yg + (size_t)(b * DCH + d) * 4096;
        const v2f vA0 = wtw((float)w * (1.0f / 8192.0f));
#pragma unroll
        for (int g = 0; g < 2; ++g) {
            const int i0 = w + 512 * g;
            const int pb = PHYS(i0);
            v2f q0 = z[pb],            q1 = z[pb + 1088],
                q2 = z[pb + 2 * 1088], q3 = z[pb + 3 * 1088],
                q4 = z[pb + 4 * 1088], q5 = z[pb + 5 * 1088],
                q6 = z[pb + 6 * 1088], q7 = z[pb + 7 * 1088];
            const v2f vA  = (g == 0) ? vA0 : cmul(vA0, mk(C1F, S1F));  // rotate e^{+i*pi/8}
            const v2f vB  = cmul(vA, vA);
            const v2f vB2 = cmul(vB, vB);
            const v2f vB3 = cmul(vB2, vB);
            v2f b1 = cmul(q1, vB), b2 = cmul(q2, vB2), b3 = cmul(q3, vB3);
            v2f t0 = q0 + b2, t1 = q0 - b2, t2 = b1 + b3;
            v2f dd = b3 - b1;
            v2f t3 = mnegi(dd);
            v2f T0 = t0 + t2, T1 = t1 + t3, T2 = t0 - t2, T3 = t1 - t3;
            b1 = cmul(q5, vB); b2 = cmul(q6, vB2); b3 = cmul(q7, vB3);
            t0 = q4 + b2; t1 = q4 - b2; t2 = b1 + b3;
            dd = b3 - b1;
            t3 = mnegi(dd);
            v2f B0 = t0 + t2, B1 = t1 + t3, B2 = t0 - t2, B3 = t1 - t3;
            yr[i0]        = T0 + cmul(B0, vA);
            yr[i0 + 1024] = T1 + cmul(B1, cmul(vA, mk(R2, R2)));
            yr[i0 + 2048] = T2 + cmul(B2, mk(-vA.y, vA.x));   // i*vA
            yr[i0 + 3072] = T3 + cmul(B3, cmul(vA, mk(-R2, R2)));
        }
    }
}

// ===================== fallback: verified 16K-FFT single-kernel path =====================
__device__ __forceinline__ int drev14(int v) {
    int r = 0;
#pragma unroll
    for (int i = 0; i < 7; ++i) { r = (r << 2) | (v & 3); v >>= 2; }
    return r;
}
__device__ __forceinline__ int drev10(int v) {
    int r = 0;
#pragma unroll
    for (int i = 0; i < 5; ++i) { r = (r << 2) | (v & 3); v >>= 2; }
    return r;
}

extern "C" __global__ void __launch_bounds__(NTH2, 4)
fftconv_v2(const float* __restrict__ hg, const float* __restrict__ xg,
           const float* __restrict__ bg, float* __restrict__ yg) {
    extern __shared__ v2f z[];
    const int w = threadIdx.x;
    const int bid = blockIdx.x;
    const int d = bid >> 2, b = bid & 3;
    const float* xr = xg + (size_t)(b * DCH + d) * 8192;
    const float* hr = hg + (size_t)d * 8192;
    v2f a[16];
    float xv[8];
    {
#pragma unroll
        for (int t = 0; t < 8; ++t) {
            xv[t] = xr[w + 1024 * t];
            float hv = hr[w + 1024 * t];
            a[t] = mk(xv[t], hv);
        }
        const float r1 = -(float)w * (1.0f / 16384.0f);
#pragma unroll
        for (int ai = 0; ai < 4; ++ai) {
            v2f u0 = a[ai], u1 = a[ai + 4];
            v2f mi3 = mk(u1.y, -u1.x);
            v2f w1 = wtw(r1 - 0.0625f * ai);
            v2f w2 = cmul(w1, w1), w3 = cmul(w2, w1);
            a[ai]      = u0 + u1;
            a[ai + 4]  = cmul(u0 + mi3, w1);
            a[ai + 8]  = cmul(u0 - u1, w2);
            a[ai + 12] = cmul(u0 - mi3, w3);
        }
        v2f v1 = wtw(4.0f * r1);
        v2f v2 = cmul(v1, v1), v3 = cmul(v2, v1);
#pragma unroll
        for (int p = 0; p < 4; ++p) {
            v2f u0 = a[4 * p], u1 = a[4 * p + 1], u2 = a[4 * p + 2], u3 = a[4 * p + 3];
            v2f t0 = u0 + u2, t1 = u1 + u3;
            v2f t2 = u0 - u2, t3 = u1 - u3;
            v2f mi3 = mnegi(t3);
            a[4 * p]     = t0 + t1;
            a[4 * p + 1] = cmul(t2 + mi3, v1);
            a[4 * p + 2] = cmul(t0 - t1, v2);
            a[4 * p + 3] = cmul(t2 - mi3, v3);
        }
        const int base = PHYS(w);
#pragma unroll
        for (int t = 0; t < 16; ++t) z[base + 1088 * t] = a[t];
    }
    __syncthreads();
    {
        const int j = w & 63, grp = w >> 6;
        const int base = PHYS(grp * 1024 + j);
#pragma unroll
        for (int t = 0; t < 16; ++t) a[t] = z[base + 68 * t];
        dif16(a, -(float)j * (1.0f / 1024.0f));
#pragma unroll
        for (int t = 0; t < 16; ++t) z[base + 68 * t] = a[t];
    }
    __syncthreads();
    {
        const int j = w & 3, grp = w >> 2;
        const int i0 = grp * 64 + j;
#pragma unroll
        for (int t = 0; t < 16; ++t) a[t] = z[PHYS(i0 + 4 * t)];
        dif16(a, -(float)j * (1.0f / 64.0f));
#pragma unroll
        for (int t = 0; t < 16; ++t) z[PHYS(i0 + 4 * t)] = a[t];
    }
    __syncthreads();
    {
        const int base = 17 * w;
#pragma unroll
        for (int t = 0; t < 16; ++t) a[t] = z[base + t];
        fwd4x4(a);
#pragma unroll
        for (int t = 0; t < 16; ++t) z[base + t] = a[t];
        __syncthreads();
        const int kw = drev10(w);
#pragma unroll
        for (int t = 0; t < 16; ++t) {
            const int rt = (((t & 3) << 2) | (t >> 2));
            const int k = (rt << 10) | kw;
            const int pp = drev14(16384 - k);
            const v2f Zm = z[PHYS(pp)];
            const v2f Zp = a[t];
            const v2f A  = mk(Zp.x + Zm.x, Zp.y - Zm.y);
            const v2f Dv = mk(Zp.x - Zm.x, Zp.y + Zm.y);
            const v2f X  = mk(0.5f * A.x, 0.5f * A.y);
            const v2f H  = mk(0.5f * Dv.y, -0.5f * Dv.x);
            a[t] = cmul(X, H);
        }
        __syncthreads();
        inv4x4(a);
#pragma unroll
        for (int t = 0; t < 16; ++t) z[base + t] = a[t];
    }
    __syncthreads();
    {
        const int j = w & 3, grp = w >> 2;
        const int i0 = grp * 64 + j;
#pragma unroll
        for (int t = 0; t < 16; ++t) a[t] = z[PHYS(i0 + 4 * t)];
        dit16(a, (float)j * (1.0f / 64.0f));
#pragma unroll
        for (int t = 0; t < 16; ++t) z[PHYS(i0 + 4 * t)] = a[t];
    }
    __syncthreads();
    {
        const int j = w & 63, grp = w >> 6;
        const int base = PHYS(grp * 1024 + j);
#pragma unroll
        for (int t = 0; t < 16; ++t) a[t] = z[base + 68 * t];
        dit16(a, (float)j * (1.0f / 1024.0f));
#pragma unroll
        for (int t = 0; t < 16; ++t) z[base + 68 * t] = a[t];
    }
    __syncthreads();
    {
        const int base = PHYS(w);
#pragma unroll
        for (int t = 0; t < 16; ++t) a[t] = z[base + 1088 * t];
        const float r1 = (float)w * (1.0f / 16384.0f);
        v2f v1 = wtw(4.0f * r1);
        v2f v2 = cmul(v1, v1), v3 = cmul(v2, v1);
#pragma unroll
        for (int p = 0; p < 4; ++p) {
            v2f b0 = a[4 * p];
            v2f b1 = cmul(a[4 * p + 1], v1);
            v2f b2 = cmul(a[4 * p + 2], v2);
            v2f b3 = cmul(a[4 * p + 3], v3);
            v2f t0 = b0 + b2, t1 = b0 - b2;
            v2f t2 = b1 + b3;
            v2f dd = b3 - b1;
            v2f t3 = mnegi(dd);
            a[4 * p]     = t0 + t2;
            a[4 * p + 1] = t1 + t3;
            a[4 * p + 2] = t0 - t2;
            a[4 * p + 3] = t1 - t3;
        }
        const float bd = bg[d];
        const float invN = 1.0f / 16384.0f;
#pragma unroll
        for (int ai = 0; ai < 4; ++ai) {
            v2f w1 = wtw(r1 + 0.0625f * ai);
            v2f w2 = cmul(w1, w1), w3 = cmul(w2, w1);
            v2f b0 = a[ai];
            v2f vv1 = cmul(a[ai + 4], w1);
            v2f vv2 = cmul(a[ai + 8], w2);
            v2f vv3 = cmul(a[ai + 12], w3);
            v2f t0 = b0 + vv2, t1 = b0 - vv2;
            v2f t2 = vv1 + vv3;
            v2f dd = vv3 - vv1;
            v2f t3 = mnegi(dd);
            v2f o0 = t0 + t2;
            v2f o1 = t1 + t3;
            yg[(size_t)(b * DCH + d) * 8192 + w + 1024 * ai]        = fmaf(xv[ai], bd, o0.x * invN);
            yg[(size_t)(b * DCH + d) * 8192 + w + 4096 + 1024 * ai] = fmaf(xv[ai + 4], bd, o1.x * invN);
        }
    }
}

extern "C" void kernel_launch(void* const* d_in, const int* in_sizes, int n_in,
                              void* d_out, int out_size, void* d_ws, size_t ws_size,
                              hipStream_t stream) {
    (void)in_sizes; (void)n_in; (void)out_size;
    const float* h = (const float*)d_in[0];
    const float* x = (const float*)d_in[1];
    const float* B = (const float*)d_in[2];
    float* y = (float*)d_out;

    const size_t need = (size_t)(DCH * NHALF + DCH) * sizeof(float2);
    if (ws_size >= need && d_ws != nullptr) {
        (void)hipFuncSetAttribute((const void*)hspec_kernel,
                                  hipFuncAttributeMaxDynamicSharedMemorySize,
                                  LDSE * (int)sizeof(float2));
        (void)hipFuncSetAttribute((const void*)fftconv_main,
                                  hipFuncAttributeMaxDynamicSharedMemorySize,
                                  LDSE * (int)sizeof(float2));
        float* wsHf = (float*)d_ws;
        float* wsNy = wsHf + 2 * (size_t)DCH * NHALF;
        hspec_kernel<<<dim3(DCH), dim3(NTH), LDSE * sizeof(float2), stream>>>(h, B, wsHf, wsNy);
        fftconv_main<<<dim3(4 * DCH), dim3(NTH), LDSE * sizeof(float2), stream>>>(x, wsHf, wsNy, y);
    } else {
        (void)hipFuncSetAttribute((const void*)fftconv_v2,
                                  hipFuncAttributeMaxDynamicSharedMemorySize,
                                  LDSE2 * (int)sizeof(float2));
        fftconv_v2<<<dim3(4 * DCH), dim3(NTH2), LDSE2 * sizeof(float2), stream>>>(h, x, B, y);
    }
}

// Round 9
// 134.371 us; speedup vs baseline: 1.0546x; 1.0022x over previous
//
#include <hip/hip_runtime.h>

#define DCH   768
#define NHALF 8192
#define NTH   512
#define PHYS(i) ((i) + ((i) >> 4))
#define LDSE  (NHALF + NHALF / 16)     // 8704 v2f = 69632 B
#define NFULL 16384
#define NTH2  1024
#define LDSE2 (NFULL + NFULL / 16)     // fallback: 17408 v2f

#define C1F 0.9238795325112867f        // cos(pi/8)
#define S1F 0.3826834323650898f        // sin(pi/8)
#define C2F 0.7071067811865476f        // cos(pi/4)

typedef float v2f __attribute__((ext_vector_type(2)));

__device__ __forceinline__ v2f mk(float x, float y) { v2f r; r.x = x; r.y = y; return r; }
__device__ __forceinline__ v2f cmul(v2f a, v2f b) {
    v2f re = a.xx * b;                       // {ax*bx, ax*by}
    return __builtin_elementwise_fma(mk(-a.y, a.y), mk(b.y, b.x), re);
}
__device__ __forceinline__ v2f mnegi(v2f t) { return mk(t.y, -t.x); }   // -i*t
__device__ __forceinline__ v2f wtw(float rev) {   // e^{2*pi*i*rev}
    return mk(__builtin_amdgcn_cosf(rev), __builtin_amdgcn_sinf(rev));
}
__device__ __forceinline__ int drev8(int v) {        // 4-digit base-4 reversal of 8-bit
    return ((v & 3) << 6) | ((v & 12) << 2) | ((v >> 2) & 12) | ((v >> 6) & 3);
}
__device__ __forceinline__ constexpr int rev2i(int a) { return ((a & 3) << 2) | ((a >> 2) & 3); }
__device__ __forceinline__ constexpr int rtof(int t)  { return ((t & 3) << 2) | (t >> 2); }

__device__ __forceinline__ v2f Ktw(int rt) {      // e^{-2*pi*i*rt/32}
    const float KC[16] = {1.0f, 0.980785280f, 0.923879533f, 0.831469612f,
                          0.707106781f, 0.555570233f, 0.382683432f, 0.195090322f,
                          0.0f, -0.195090322f, -0.382683432f, -0.555570233f,
                          -0.707106781f, -0.831469612f, -0.923879533f, -0.980785280f};
    const float KS[16] = {0.0f, -0.195090322f, -0.382683432f, -0.555570233f,
                          -0.707106781f, -0.831469612f, -0.923879533f, -0.980785280f,
                          -1.0f, -0.980785280f, -0.923879533f, -0.831469612f,
                          -0.707106781f, -0.555570233f, -0.382683432f, -0.195090322f};
    return mk(KC[rt], KS[rt]);
}

// -------- fused radix-16 DIF (levels m1=4*m2 then m2); r1 = -j/(16*m2)
__device__ __forceinline__ void dif16(v2f* a, float r1) {
    const v2f w10 = wtw(r1);
    const v2f sq  = cmul(w10, w10);
    const v2f cu  = cmul(sq, w10);
#pragma unroll
    for (int ai = 0; ai < 4; ++ai) {
        v2f w1, w2, w3;
        if (ai == 0)      { w1 = w10; w2 = sq; w3 = cu; }
        else if (ai == 1) { w1 = cmul(w10, mk(C1F, -S1F));
                            w2 = cmul(sq,  mk(C2F, -C2F));
                            w3 = cmul(cu,  mk(S1F, -C1F)); }
        else if (ai == 2) { w1 = cmul(w10, mk(C2F, -C2F));
                            w2 = mk(sq.y, -sq.x);           // sq * (-i)
                            w3 = cmul(cu,  mk(-C2F, -C2F)); }
        else              { w1 = cmul(w10, mk(S1F, -C1F));
                            w2 = cmul(sq,  mk(-C2F, -C2F));
                            w3 = cmul(cu,  mk(-C1F,  S1F)); }
        v2f u0 = a[ai], u1 = a[ai + 4], u2 = a[ai + 8], u3 = a[ai + 12];
        v2f t0 = u0 + u2, t1 = u1 + u3;
        v2f t2 = u0 - u2, t3 = u1 - u3;
        v2f mi3 = mnegi(t3);
        a[ai]      = t0 + t1;
        a[ai + 4]  = cmul(t2 + mi3, w1);
        a[ai + 8]  = cmul(t0 - t1, w2);
        a[ai + 12] = cmul(t2 - mi3, w3);
    }
    const v2f v1 = cmul(sq, sq);                  // w10^4
    const v2f v2 = cmul(v1, v1);
    const v2f v3 = cmul(v2, v1);
#pragma unroll
    for (int p = 0; p < 4; ++p) {
        v2f u0 = a[4 * p], u1 = a[4 * p + 1], u2 = a[4 * p + 2], u3 = a[4 * p + 3];
        v2f t0 = u0 + u2, t1 = u1 + u3;
        v2f t2 = u0 - u2, t3 = u1 - u3;
        v2f mi3 = mnegi(t3);
        a[4 * p]     = t0 + t1;
        a[4 * p + 1] = cmul(t2 + mi3, v1);
        a[4 * p + 2] = cmul(t0 - t1, v2);
        a[4 * p + 3] = cmul(t2 - mi3, v3);
    }
}
// -------- fused inverse radix-16 (levels m2 then m1=4*m2); r1 = +j/(16*m2)
__device__ __forceinline__ void dit16(v2f* a, float r1) {
    const v2f w10 = wtw(r1);
    const v2f sq  = cmul(w10, w10);
    const v2f cu  = cmul(sq, w10);
    const v2f v1  = cmul(sq, sq);
    const v2f v2  = cmul(v1, v1);
    const v2f v3  = cmul(v2, v1);
#pragma unroll
    for (int p = 0; p < 4; ++p) {
        v2f b0 = a[4 * p];
        v2f b1 = cmul(a[4 * p + 1], v1);
        v2f b2 = cmul(a[4 * p + 2], v2);
        v2f b3 = cmul(a[4 * p + 3], v3);
        v2f t0 = b0 + b2, t1 = b0 - b2;
        v2f t2 = b1 + b3;
        v2f dd = b3 - b1;
        v2f t3 = mnegi(dd);
        a[4 * p]     = t0 + t2;
        a[4 * p + 1] = t1 + t3;
        a[4 * p + 2] = t0 - t2;
        a[4 * p + 3] = t1 - t3;
    }
#pragma unroll
    for (int ai = 0; ai < 4; ++ai) {
        v2f w1, w2, w3;
        if (ai == 0)      { w1 = w10; w2 = sq; w3 = cu; }
        else if (ai == 1) { w1 = cmul(w10, mk(C1F, S1F));
                            w2 = cmul(sq,  mk(C2F, C2F));
                            w3 = cmul(cu,  mk(S1F, C1F)); }
        else if (ai == 2) { w1 = cmul(w10, mk(C2F, C2F));
                            w2 = mk(-sq.y, sq.x);           // sq * (+i)
                            w3 = cmul(cu,  mk(-C2F, C2F)); }
        else              { w1 = cmul(w10, mk(S1F, C1F));
                            w2 = cmul(sq,  mk(-C2F, C2F));
                            w3 = cmul(cu,  mk(-C1F, -S1F)); }
        v2f b0 = a[ai];
        v2f b1 = cmul(a[ai + 4], w1);
        v2f b2 = cmul(a[ai + 8], w2);
        v2f b3 = cmul(a[ai + 12], w3);
        v2f t0 = b0 + b2, t1 = b0 - b2;
        v2f t2 = b1 + b3;
        v2f dd = b3 - b1;
        v2f t3 = mnegi(dd);
        a[ai]      = t0 + t2;
        a[ai + 4]  = t1 + t3;
        a[ai + 8]  = t0 - t2;
        a[ai + 12] = t1 - t3;
    }
}
__device__ __forceinline__ void fwd4x4(v2f* a) {   // radix-4 DIF, m=1, twiddle-free
#pragma unroll
    for (int u = 0; u < 4; ++u) {
        v2f u0 = a[4*u], u1 = a[4*u+1], u2 = a[4*u+2], u3 = a[4*u+3];
        v2f t0 = u0 + u2, t1 = u1 + u3, t2 = u0 - u2, t3 = u1 - u3;
        v2f mi3 = mnegi(t3);
        a[4*u] = t0 + t1; a[4*u+1] = t2 + mi3;
        a[4*u+2] = t0 - t1; a[4*u+3] = t2 - mi3;
    }
}
__device__ __forceinline__ void inv4x4(v2f* a) {   // inverse radix-4, m=1
#pragma unroll
    for (int u = 0; u < 4; ++u) {
        v2f b0 = a[4*u], b1 = a[4*u+1], b2 = a[4*u+2], b3 = a[4*u+3];
        v2f t0 = b0 + b2, t1 = b0 - b2, t2 = b1 + b3;
        v2f dd = b3 - b1;
        v2f t3 = mnegi(dd);
        a[4*u] = t0 + t2; a[4*u+1] = t1 + t3;
        a[4*u+2] = t0 - t2; a[4*u+3] = t1 - t3;
    }
}

// ======== hspec's forward 8192-pt FFT — round-5-exact path (loads inline, full publish)
__device__ __forceinline__ void fwd8k_h(const v2f* __restrict__ src,
                                        v2f* __restrict__ z, const int w, v2f* a) {
    const float R2 = 0.70710678118654752f;
#pragma unroll
    for (int g = 0; g < 2; ++g) {
        const int i0 = w + 512 * g;
        v2f c0 = src[i0], c1 = src[i0 + 1024], c2 = src[i0 + 2048], c3 = src[i0 + 3072];
        const v2f wA  = wtw(-(float)i0 * (1.0f / 8192.0f));
        const v2f wB  = cmul(wA, wA);
        const v2f wB2 = cmul(wB, wB);
        const v2f wB3 = cmul(wB2, wB);
        const int pb = PHYS(i0);
        v2f t0 = c0 + c2, t1 = c1 + c3, t2 = c0 - c2, t3 = c1 - c3;
        v2f mi3 = mnegi(t3);
        z[pb]            = t0 + t1;
        z[pb + 1088]     = cmul(t2 + mi3, wB);
        z[pb + 2 * 1088] = cmul(t0 - t1, wB2);
        z[pb + 3 * 1088] = cmul(t2 - mi3, wB3);
        v2f d0 = cmul(c0, wA);
        v2f d1 = cmul(c1, cmul(wA, mk(R2, -R2)));
        v2f d2 = cmul(c2, mk(wA.y, -wA.x));           // -i*wA
        v2f d3 = cmul(c3, cmul(wA, mk(-R2, -R2)));
        t0 = d0 + d2; t1 = d1 + d3; t2 = d0 - d2; t3 = d1 - d3;
        mi3 = mnegi(t3);
        z[pb + 4 * 1088] = t0 + t1;
        z[pb + 5 * 1088] = cmul(t2 + mi3, wB);
        z[pb + 6 * 1088] = cmul(t0 - t1, wB2);
        z[pb + 7 * 1088] = cmul(t2 - mi3, wB3);
    }
    __syncthreads();
    {
        const int j = w & 63, blk = w >> 6;
        const int base = PHYS(blk * 1024 + j);
#pragma unroll
        for (int t = 0; t < 16; ++t) a[t] = z[base + 68 * t];
        dif16(a, -(float)j * (1.0f / 1024.0f));
#pragma unroll
        for (int t = 0; t < 16; ++t) z[base + 68 * t] = a[t];
    }
    __syncthreads();
    {
        const int j = w & 3, g = w >> 2;
        const int i0 = g * 64 + j;
#pragma unroll
        for (int t = 0; t < 16; ++t) a[t] = z[PHYS(i0 + 4 * t)];
        dif16(a, -(float)j * (1.0f / 64.0f));
#pragma unroll
        for (int t = 0; t < 16; ++t) z[PHYS(i0 + 4 * t)] = a[t];
    }
    __syncthreads();
    {
        const int base = 17 * w;
#pragma unroll
        for (int t = 0; t < 16; ++t) a[t] = z[base + t];
        fwd4x4(a);
#pragma unroll
        for (int t = 0; t < 16; ++t) z[base + t] = a[t];
    }
    __syncthreads();
}

// ======== main's forward 8192-pt FFT — r8 path (preloaded c[8], publish 8 non-owner)
__device__ __forceinline__ void fwd8k_m(const v2f* __restrict__ c,
                                        v2f* __restrict__ z, const int w, v2f* a) {
    const float R2 = 0.70710678118654752f;
    const v2f wA0 = wtw(-(float)w * (1.0f / 8192.0f));
#pragma unroll
    for (int g = 0; g < 2; ++g) {
        const int i0 = w + 512 * g;
        v2f c0 = c[4*g], c1 = c[4*g+1], c2 = c[4*g+2], c3 = c[4*g+3];
        const v2f wA  = (g == 0) ? wA0 : cmul(wA0, mk(C1F, -S1F));  // rotate by e^{-i*pi/8}
        const v2f wB  = cmul(wA, wA);
        const v2f wB2 = cmul(wB, wB);
        const v2f wB3 = cmul(wB2, wB);
        const int pb = PHYS(i0);
        v2f t0 = c0 + c2, t1 = c1 + c3, t2 = c0 - c2, t3 = c1 - c3;
        v2f mi3 = mnegi(t3);
        z[pb]            = t0 + t1;
        z[pb + 1088]     = cmul(t2 + mi3, wB);
        z[pb + 2 * 1088] = cmul(t0 - t1, wB2);
        z[pb + 3 * 1088] = cmul(t2 - mi3, wB3);
        v2f d0 = cmul(c0, wA);
        v2f d1 = cmul(c1, cmul(wA, mk(R2, -R2)));
        v2f d2 = cmul(c2, mk(wA.y, -wA.x));           // -i*wA
        v2f d3 = cmul(c3, cmul(wA, mk(-R2, -R2)));
        t0 = d0 + d2; t1 = d1 + d3; t2 = d0 - d2; t3 = d1 - d3;
        mi3 = mnegi(t3);
        z[pb + 4 * 1088] = t0 + t1;
        z[pb + 5 * 1088] = cmul(t2 + mi3, wB);
        z[pb + 6 * 1088] = cmul(t0 - t1, wB2);
        z[pb + 7 * 1088] = cmul(t2 - mi3, wB3);
    }
    __syncthreads();
    {
        const int j = w & 63, blk = w >> 6;
        const int base = PHYS(blk * 1024 + j);
#pragma unroll
        for (int t = 0; t < 16; ++t) a[t] = z[base + 68 * t];
        dif16(a, -(float)j * (1.0f / 1024.0f));
#pragma unroll
        for (int t = 0; t < 16; ++t) z[base + 68 * t] = a[t];
    }
    __syncthreads();
    {
        const int j = w & 3, g = w >> 2;
        const int i0 = g * 64 + j;
#pragma unroll
        for (int t = 0; t < 16; ++t) a[t] = z[PHYS(i0 + 4 * t)];
        dif16(a, -(float)j * (1.0f / 64.0f));
#pragma unroll
        for (int t = 0; t < 16; ++t) z[PHYS(i0 + 4 * t)] = a[t];
    }
    __syncthreads();
    {
        const int base = 17 * w;
#pragma unroll
        for (int t = 0; t < 16; ++t) a[t] = z[base + t];
        fwd4x4(a);
#pragma unroll
        for (int t = 0; t < 16; ++t)
            if ((t & 3) > 1) z[base + t] = a[t];     // publish non-owner slots only
    }
    __syncthreads();
}

// ============ kernel 1: per-channel H spectrum, scaled by 1/N, H += B (round-5 exact)
extern "C" __global__ void __launch_bounds__(NTH, 4)
hspec_kernel(const float* __restrict__ hg, const float* __restrict__ bg,
             float* __restrict__ wsHf, float* __restrict__ wsNy) {
    extern __shared__ v2f z[];
    const int w = threadIdx.x;
    const int d = blockIdx.x;
    const v2f* hr = (const v2f*)hg + (size_t)d * 4096;
    v2f a[16];
    fwd8k_h(hr, z, w, a);

    const float Bd = bg[d];
    const float invN = 1.0f / 16384.0f;
    v2f* out = (v2f*)wsHf + (size_t)d * NHALF;
    const int wm = w & 255, whi = w >> 8;
    const int k0 = 2 * drev8(wm) + whi;
    const v2f wk0 = wtw(-(float)k0 * (1.0f / 16384.0f));
    int qm = 0;
    if (w != 0) { const int bq = (512 - k0) >> 1; qm = (whi << 8) | drev8(bq); }
#pragma unroll
    for (int t = 0; t < 16; ++t) {
        const int rt = rtof(t);
        if (w == 0 && t == 0) {
            v2f C0 = a[0];
            out[0] = mk((C0.x + C0.y + Bd) * invN, 0.0f);
            ((v2f*)wsNy)[d] = mk((C0.x - C0.y + Bd) * invN, 0.0f);
        } else {
            const int cq = (w == 0) ? rev2i(16 - rt) : rev2i(15 - rt);
            const v2f Cq = z[17 * qm + cq];
            const v2f Cp = a[t];
            const v2f cA = mk(0.5f * (Cp.x + Cq.x), 0.5f * (Cp.y - Cq.y));
            const v2f cB = mk(0.5f * (Cp.y + Cq.y), -0.5f * (Cp.x - Cq.x));
            const v2f Wk = cmul(wk0, Ktw(rt));
            const v2f Hf = cA + cmul(Wk, cB);
            out[(t << 9) + w] = mk((Hf.x + Bd) * invN, Hf.y * invN);
        }
    }
}

// ============ kernel 2: main conv (round-8 exact)
extern "C" __global__ void __launch_bounds__(NTH, 4)
fftconv_main(const float* __restrict__ xg, const float* __restrict__ wsHf,
             const float* __restrict__ wsNy, float* __restrict__ yg) {
    extern __shared__ v2f z[];
    const int w = threadIdx.x;
    const int bid = blockIdx.x;
    const int d = bid >> 2, b = bid & 3;
    const v2f* xr = (const v2f*)xg + (size_t)(b * DCH + d) * 4096;
    const v2f* hrow = (const v2f*)wsHf + (size_t)d * NHALF;
    const float R2 = 0.70710678118654752f;
    v2f a[16], c[8];

    // ---- x loads FIRST (vmcnt retires in order: H gathers must not gate P1)
#pragma unroll
    for (int g = 0; g < 2; ++g)
#pragma unroll
        for (int t = 0; t < 4; ++t) c[4*g + t] = xr[w + 512*g + 1024*t];

    // ---- prefetch H-spectrum operands for P4b (latency hides under P1..P4a)
    const int wm = w & 255, whi = w >> 8;
    const int k0 = 2 * drev8(wm) + whi;
    int qm = 0;
    if (w != 0) { const int bq = (512 - k0) >> 1; qm = (whi << 8) | drev8(bq); }
    v2f hp[8], hq[8];
#pragma unroll
    for (int u = 0; u < 8; ++u) {
        const int t = ((u >> 1) << 2) | (u & 1);      // owner t: 0,1,4,5,8,9,12,13
        const int rt = rtof(t);
        const int cq = (w == 0) ? rev2i(16 - rt) : rev2i(15 - rt);
        hp[u] = hrow[(t << 9) + w];
        hq[u] = hrow[(cq << 9) + qm];
    }
    v2f hn = ((const v2f*)wsNy)[d];
    asm volatile("" :: "v"(hp[0]), "v"(hp[1]), "v"(hp[2]), "v"(hp[3]),
                       "v"(hp[4]), "v"(hp[5]), "v"(hp[6]), "v"(hp[7]));
    asm volatile("" :: "v"(hq[0]), "v"(hq[1]), "v"(hq[2]), "v"(hq[3]),
                       "v"(hq[4]), "v"(hq[5]), "v"(hq[6]), "v"(hq[7]), "v"(hn));

    fwd8k_m(c, z, w, a);

    // ---- P4b: pair-owner combine; owner Wtil stays in regs, partner to LDS
    {
        const v2f wk0 = wtw(-(float)k0 * (1.0f / 16384.0f));
        int u = 0;
#pragma unroll
        for (int t = 0; t < 16; ++t) {
            if ((t & 3) > 1) continue;           // owner elements: rt < 8
            const int rt = rtof(t);
            if (w == 0 && t == 0) {
                v2f C0 = a[0];
                float X0 = C0.x + C0.y, XN = C0.x - C0.y;
                v2f Y1 = mk(X0 * hp[0].x, X0 * hp[0].y);
                v2f Y2 = mk(XN * hn.x, XN * hn.y);
                v2f S  = mk(Y1.x + Y2.x, Y1.y - Y2.y);
                v2f Dd = mk(Y1.x - Y2.x, Y1.y + Y2.y);
                a[0] = mk(S.x - Dd.y, S.y + Dd.x);
            } else {
                const int cq = (w == 0) ? rev2i(16 - rt) : rev2i(15 - rt);
                const v2f Cq = z[17 * qm + cq];
                const v2f Cp = a[t];
                const v2f cA = mk(0.5f * (Cp.x + Cq.x), 0.5f * (Cp.y - Cq.y));
                const v2f cB = mk(0.5f * (Cp.y + Cq.y), -0.5f * (Cp.x - Cq.x));
                const v2f Wk = cmul(wk0, Ktw(rt));
                const v2f T  = cmul(Wk, cB);
                const v2f X1 = cA + T;
                const v2f X2 = mk(cA.x - T.x, -(cA.y - T.y));  // conj(cA - T)
                const v2f Y1 = cmul(X1, hp[u]);
                const v2f Y2 = cmul(X2, hq[u]);
                const v2f S  = mk(Y1.x + Y2.x, Y1.y - Y2.y);
                const v2f Dd = mk(Y1.x - Y2.x, Y1.y + Y2.y);
                const v2f Vk = mk(Wk.x, -Wk.y);
                const v2f U  = cmul(Vk, Dd);
                a[t]            = mk(S.x - U.y, S.y + U.x);     // own Wtil[k]
                z[17 * qm + cq] = mk(S.x + U.y, U.x - S.y);     // partner Wtil
            }
            ++u;
        }
        if (w == 0) {   // self-pair k = 4096 (position 2)
            const v2f Cp = z[2];
            const v2f cA = mk(Cp.x, 0.0f);
            const v2f cB = mk(Cp.y, 0.0f);
            const v2f Wk = mk(0.0f, -1.0f);
            const v2f T  = cmul(Wk, cB);
            const v2f X1 = cA + T;
            const v2f X2 = mk(cA.x - T.x, -(cA.y - T.y));
            const v2f Hp = hrow[(2 << 9)];
            const v2f Y1 = cmul(X1, Hp);
            const v2f Y2 = cmul(X2, Hp);
            const v2f S  = mk(Y1.x + Y2.x, Y1.y - Y2.y);
            const v2f Dd = mk(Y1.x - Y2.x, Y1.y + Y2.y);
            const v2f Vk = mk(0.0f, 1.0f);
            const v2f U  = cmul(Vk, Dd);
            z[2] = mk(S.x - U.y, S.y + U.x);
        }
    }
    __syncthreads();
    // ---- inverse radix-4 (m=1): own 8 from regs, missing 8 from LDS
    {
        const int base = 17 * w;
#pragma unroll
        for (int t = 0; t < 16; ++t)
            if ((t & 3) > 1) a[t] = z[base + t];
        inv4x4(a);
#pragma unroll
        for (int t = 0; t < 16; ++t) z[base + t] = a[t];
    }
    __syncthreads();
    // ---- P5: inverse radix-16, m2 = 4
    {
        const int j = w & 3, g = w >> 2;
        const int i0 = g * 64 + j;
#pragma unroll
        for (int t = 0; t < 16; ++t) a[t] = z[PHYS(i0 + 4 * t)];
        dit16(a, (float)j * (1.0f / 64.0f));
#pragma unroll
        for (int t = 0; t < 16; ++t) z[PHYS(i0 + 4 * t)] = a[t];
    }
    __syncthreads();
    // ---- P6: inverse radix-16, m2 = 64
    {
        const int j = w & 63, blk = w >> 6;
        const int base = PHYS(blk * 1024 + j);
#pragma unroll
        for (int t = 0; t < 16; ++t) a[t] = z[base + 68 * t];
        dit16(a, (float)j * (1.0f / 1024.0f));
#pragma unroll
        for (int t = 0; t < 16; ++t) z[base + 68 * t] = a[t];
    }
    __syncthreads();
    // ---- P7: inverse radix-4(m=1024) + inverse radix-2(m=4096), store y
    {
        v2f* yr = (v2f*)yg + (size_t)(b * DCH + d) * 4096;
        const v2f vA0 = wtw((float)w * (1.0f / 8192.0f));
#pragma unroll
        for (int g = 0; g < 2; ++g) {
            const int i0 = w + 512 * g;
            const int pb = PHYS(i0);
            v2f q0 = z[pb],            q1 = z[pb + 1088],
                q2 = z[pb + 2 * 1088], q3 = z[pb + 3 * 1088],
                q4 = z[pb + 4 * 1088], q5 = z[pb + 5 * 1088],
                q6 = z[pb + 6 * 1088], q7 = z[pb + 7 * 1088];
            const v2f vA  = (g == 0) ? vA0 : cmul(vA0, mk(C1F, S1F));  // rotate e^{+i*pi/8}
            const v2f vB  = cmul(vA, vA);
            const v2f vB2 = cmul(vB, vB);
            const v2f vB3 = cmul(vB2, vB);
            v2f b1 = cmul(q1, vB), b2 = cmul(q2, vB2), b3 = cmul(q3, vB3);
            v2f t0 = q0 + b2, t1 = q0 - b2, t2 = b1 + b3;
            v2f dd = b3 - b1;
            v2f t3 = mnegi(dd);
            v2f T0 = t0 + t2, T1 = t1 + t3, T2 = t0 - t2, T3 = t1 - t3;
            b1 = cmul(q5, vB); b2 = cmul(q6, vB2); b3 = cmul(q7, vB3);
            t0 = q4 + b2; t1 = q4 - b2; t2 = b1 + b3;
            dd = b3 - b1;
            t3 = mnegi(dd);
            v2f B0 = t0 + t2, B1 = t1 + t3, B2 = t0 - t2, B3 = t1 - t3;
            yr[i0]        = T0 + cmul(B0, vA);
            yr[i0 + 1024] = T1 + cmul(B1, cmul(vA, mk(R2, R2)));
            yr[i0 + 2048] = T2 + cmul(B2, mk(-vA.y, vA.x));   // i*vA
            yr[i0 + 3072] = T3 + cmul(B3, cmul(vA, mk(-R2, R2)));
        }
    }
}

// ===================== fallback: verified 16K-FFT single-kernel path =====================
__device__ __forceinline__ int drev14(int v) {
    int r = 0;
#pragma unroll
    for (int i = 0; i < 7; ++i) { r = (r << 2) | (v & 3); v >>= 2; }
    return r;
}
__device__ __forceinline__ int drev10(int v) {
    int r = 0;
#pragma unroll
    for (int i = 0; i < 5; ++i) { r = (r << 2) | (v & 3); v >>= 2; }
    return r;
}

extern "C" __global__ void __launch_bounds__(NTH2, 4)
fftconv_v2(const float* __restrict__ hg, const float* __restrict__ xg,
           const float* __restrict__ bg, float* __restrict__ yg) {
    extern __shared__ v2f z[];
    const int w = threadIdx.x;
    const int bid = blockIdx.x;
    const int d = bid >> 2, b = bid & 3;
    const float* xr = xg + (size_t)(b * DCH + d) * 8192;
    const float* hr = hg + (size_t)d * 8192;
    v2f a[16];
    float xv[8];
    {
#pragma unroll
        for (int t = 0; t < 8; ++t) {
            xv[t] = xr[w + 1024 * t];
            float hv = hr[w + 1024 * t];
            a[t] = mk(xv[t], hv);
        }
        const float r1 = -(float)w * (1.0f / 16384.0f);
#pragma unroll
        for (int ai = 0; ai < 4; ++ai) {
            v2f u0 = a[ai], u1 = a[ai + 4];
            v2f mi3 = mk(u1.y, -u1.x);
            v2f w1 = wtw(r1 - 0.0625f * ai);
            v2f w2 = cmul(w1, w1), w3 = cmul(w2, w1);
            a[ai]      = u0 + u1;
            a[ai + 4]  = cmul(u0 + mi3, w1);
            a[ai + 8]  = cmul(u0 - u1, w2);
            a[ai + 12] = cmul(u0 - mi3, w3);
        }
        v2f v1 = wtw(4.0f * r1);
        v2f v2 = cmul(v1, v1), v3 = cmul(v2, v1);
#pragma unroll
        for (int p = 0; p < 4; ++p) {
            v2f u0 = a[4 * p], u1 = a[4 * p + 1], u2 = a[4 * p + 2], u3 = a[4 * p + 3];
            v2f t0 = u0 + u2, t1 = u1 + u3;
            v2f t2 = u0 - u2, t3 = u1 - u3;
            v2f mi3 = mnegi(t3);
            a[4 * p]     = t0 + t1;
            a[4 * p + 1] = cmul(t2 + mi3, v1);
            a[4 * p + 2] = cmul(t0 - t1, v2);
            a[4 * p + 3] = cmul(t2 - mi3, v3);
        }
        const int base = PHYS(w);
#pragma unroll
        for (int t = 0; t < 16; ++t) z[base + 1088 * t] = a[t];
    }
    __syncthreads();
    {
        const int j = w & 63, grp = w >> 6;
        const int base = PHYS(grp * 1024 + j);
#pragma unroll
        for (int t = 0; t < 16; ++t) a[t] = z[base + 68 * t];
        dif16(a, -(float)j * (1.0f / 1024.0f));
#pragma unroll
        for (int t = 0; t < 16; ++t) z[base + 68 * t] = a[t];
    }
    __syncthreads();
    {
        const int j = w & 3, grp = w >> 2;
        const int i0 = grp * 64 + j;
#pragma unroll
        for (int t = 0; t < 16; ++t) a[t] = z[PHYS(i0 + 4 * t)];
        dif16(a, -(float)j * (1.0f / 64.0f));
#pragma unroll
        for (int t = 0; t < 16; ++t) z[PHYS(i0 + 4 * t)] = a[t];
    }
    __syncthreads();
    {
        const int base = 17 * w;
#pragma unroll
        for (int t = 0; t < 16; ++t) a[t] = z[base + t];
        fwd4x4(a);
#pragma unroll
        for (int t = 0; t < 16; ++t) z[base + t] = a[t];
        __syncthreads();
        const int kw = drev10(w);
#pragma unroll
        for (int t = 0; t < 16; ++t) {
            const int rt = (((t & 3) << 2) | (t >> 2));
            const int k = (rt << 10) | kw;
            const int pp = drev14(16384 - k);
            const v2f Zm = z[PHYS(pp)];
            const v2f Zp = a[t];
            const v2f A  = mk(Zp.x + Zm.x, Zp.y - Zm.y);
            const v2f Dv = mk(Zp.x - Zm.x, Zp.y + Zm.y);
            const v2f X  = mk(0.5f * A.x, 0.5f * A.y);
            const v2f H  = mk(0.5f * Dv.y, -0.5f * Dv.x);
            a[t] = cmul(X, H);
        }
        __syncthreads();
        inv4x4(a);
#pragma unroll
        for (int t = 0; t < 16; ++t) z[base + t] = a[t];
    }
    __syncthreads();
    {
        const int j = w & 3, grp = w >> 2;
        const int i0 = grp * 64 + j;
#pragma unroll
        for (int t = 0; t < 16; ++t) a[t] = z[PHYS(i0 + 4 * t)];
        dit16(a, (float)j * (1.0f / 64.0f));
#pragma unroll
        for (int t = 0; t < 16; ++t) z[PHYS(i0 + 4 * t)] = a[t];
    }
    __syncthreads();
    {
        const int j = w & 63, grp = w >> 6;
        const int base = PHYS(grp * 1024 + j);
#pragma unroll
        for (int t = 0; t < 16; ++t) a[t] = z[base + 68 * t];
        dit16(a, (float)j * (1.0f / 1024.0f));
#pragma unroll
        for (int t = 0; t < 16; ++t) z[base + 68 * t] = a[t];
    }
    __syncthreads();
    {
        const int base = PHYS(w);
#pragma unroll
        for (int t = 0; t < 16; ++t) a[t] = z[base + 1088 * t];
        const float r1 = (float)w * (1.0f / 16384.0f);
        v2f v1 = wtw(4.0f * r1);
        v2f v2 = cmul(v1, v1), v3 = cmul(v2, v1);
#pragma unroll
        for (int p = 0; p < 4; ++p) {
            v2f b0 = a[4 * p];
            v2f b1 = cmul(a[4 * p + 1], v1);
            v2f b2 = cmul(a[4 * p + 2], v2);
            v2f b3 = cmul(a[4 * p + 3], v3);
            v2f t0 = b0 + b2, t1 = b0 - b2;
            v2f t2 = b1 + b3;
            v2f dd = b3 - b1;
            v2f t3 = mnegi(dd);
            a[4 * p]     = t0 + t2;
            a[4 * p + 1] = t1 + t3;
            a[4 * p + 2] = t0 - t2;
            a[4 * p + 3] = t1 - t3;
        }
        const float bd = bg[d];
        const float invN = 1.0f / 16384.0f;
#pragma unroll
        for (int ai = 0; ai < 4; ++ai) {
            v2f w1 = wtw(r1 + 0.0625f * ai);
            v2f w2 = cmul(w1, w1), w3 = cmul(w2, w1);
            v2f b0 = a[ai];
            v2f vv1 = cmul(a[ai + 4], w1);
            v2f vv2 = cmul(a[ai + 8], w2);
            v2f vv3 = cmul(a[ai + 12], w3);
            v2f t0 = b0 + vv2, t1 = b0 - vv2;
            v2f t2 = vv1 + vv3;
            v2f dd = vv3 - vv1;
            v2f t3 = mnegi(dd);
            v2f o0 = t0 + t2;
            v2f o1 = t1 + t3;
            yg[(size_t)(b * DCH + d) * 8192 + w + 1024 * ai]        = fmaf(xv[ai], bd, o0.x * invN);
            yg[(size_t)(b * DCH + d) * 8192 + w + 4096 + 1024 * ai] = fmaf(xv[ai + 4], bd, o1.x * invN);
        }
    }
}

extern "C" void kernel_launch(void* const* d_in, const int* in_sizes, int n_in,
                              void* d_out, int out_size, void* d_ws, size_t ws_size,
                              hipStream_t stream) {
    (void)in_sizes; (void)n_in; (void)out_size;
    const float* h = (const float*)d_in[0];
    const float* x = (const float*)d_in[1];
    const float* B = (const float*)d_in[2];
    float* y = (float*)d_out;

    const size_t need = (size_t)(DCH * NHALF + DCH) * sizeof(float2);
    if (ws_size >= need && d_ws != nullptr) {
        (void)hipFuncSetAttribute((const void*)hspec_kernel,
                                  hipFuncAttributeMaxDynamicSharedMemorySize,
                                  LDSE * (int)sizeof(float2));
        (void)hipFuncSetAttribute((const void*)fftconv_main,
                                  hipFuncAttributeMaxDynamicSharedMemorySize,
                                  LDSE * (int)sizeof(float2));
        float* wsHf = (float*)d_ws;
        float* wsNy = wsHf + 2 * (size_t)DCH * NHALF;
        hspec_kernel<<<dim3(DCH), dim3(NTH), LDSE * sizeof(float2), stream>>>(h, B, wsHf, wsNy);
        fftconv_main<<<dim3(4 * DCH), dim3(NTH), LDSE * sizeof(float2), stream>>>(x, wsHf, wsNy, y);
    } else {
        (void)hipFuncSetAttribute((const void*)fftconv_v2,
                                  hipFuncAttributeMaxDynamicSharedMemorySize,
                                  LDSE2 * (int)sizeof(float2));
        fftconv_v2<<<dim3(4 * DCH), dim3(NTH2), LDSE2 * sizeof(float2), stream>>>(h, x, B, y);
    }
}

// Round 10
// 132.912 us; speedup vs baseline: 1.0662x; 1.0110x over previous
//
#include <hip/hip_runtime.h>

#define DCH   768
#define NHALF 8192
#define NTH   512
#define PHYS(i) ((i) + ((i) >> 4))
#define LDSE  (NHALF + NHALF / 16)     // 8704 v2f = 69632 B
#define NFULL 16384
#define NTH2  1024
#define LDSE2 (NFULL + NFULL / 16)     // fallback: 17408 v2f

#define C1F 0.9238795325112867f        // cos(pi/8)
#define S1F 0.3826834323650898f        // sin(pi/8)
#define C2F 0.7071067811865476f        // cos(pi/4)

typedef float v2f __attribute__((ext_vector_type(2)));

__device__ __forceinline__ v2f mk(float x, float y) { v2f r; r.x = x; r.y = y; return r; }
__device__ __forceinline__ v2f cmul(v2f a, v2f b) {
    v2f re = a.xx * b;                       // {ax*bx, ax*by}
    return __builtin_elementwise_fma(mk(-a.y, a.y), mk(b.y, b.x), re);
}
__device__ __forceinline__ v2f mnegi(v2f t) { return mk(t.y, -t.x); }   // -i*t
__device__ __forceinline__ v2f wtw(float rev) {   // e^{2*pi*i*rev}
    return mk(__builtin_amdgcn_cosf(rev), __builtin_amdgcn_sinf(rev));
}
__device__ __forceinline__ int drev8(int v) {        // 4-digit base-4 reversal of 8-bit
    return ((v & 3) << 6) | ((v & 12) << 2) | ((v >> 2) & 12) | ((v >> 6) & 3);
}
__device__ __forceinline__ constexpr int rev2i(int a) { return ((a & 3) << 2) | ((a >> 2) & 3); }
__device__ __forceinline__ constexpr int rtof(int t)  { return ((t & 3) << 2) | (t >> 2); }

__device__ __forceinline__ v2f Ktw(int rt) {      // e^{-2*pi*i*rt/32}
    const float KC[16] = {1.0f, 0.980785280f, 0.923879533f, 0.831469612f,
                          0.707106781f, 0.555570233f, 0.382683432f, 0.195090322f,
                          0.0f, -0.195090322f, -0.382683432f, -0.555570233f,
                          -0.707106781f, -0.831469612f, -0.923879533f, -0.980785280f};
    const float KS[16] = {0.0f, -0.195090322f, -0.382683432f, -0.555570233f,
                          -0.707106781f, -0.831469612f, -0.923879533f, -0.980785280f,
                          -1.0f, -0.980785280f, -0.923879533f, -0.831469612f,
                          -0.707106781f, -0.555570233f, -0.382683432f, -0.195090322f};
    return mk(KC[rt], KS[rt]);
}

// -------- fused radix-16 DIF (levels m1=4*m2 then m2); r1 = -j/(16*m2)
__device__ __forceinline__ void dif16(v2f* a, float r1) {
    const v2f w10 = wtw(r1);
    const v2f sq  = cmul(w10, w10);
    const v2f cu  = cmul(sq, w10);
#pragma unroll
    for (int ai = 0; ai < 4; ++ai) {
        v2f w1, w2, w3;
        if (ai == 0)      { w1 = w10; w2 = sq; w3 = cu; }
        else if (ai == 1) { w1 = cmul(w10, mk(C1F, -S1F));
                            w2 = cmul(sq,  mk(C2F, -C2F));
                            w3 = cmul(cu,  mk(S1F, -C1F)); }
        else if (ai == 2) { w1 = cmul(w10, mk(C2F, -C2F));
                            w2 = mk(sq.y, -sq.x);           // sq * (-i)
                            w3 = cmul(cu,  mk(-C2F, -C2F)); }
        else              { w1 = cmul(w10, mk(S1F, -C1F));
                            w2 = cmul(sq,  mk(-C2F, -C2F));
                            w3 = cmul(cu,  mk(-C1F,  S1F)); }
        v2f u0 = a[ai], u1 = a[ai + 4], u2 = a[ai + 8], u3 = a[ai + 12];
        v2f t0 = u0 + u2, t1 = u1 + u3;
        v2f t2 = u0 - u2, t3 = u1 - u3;
        v2f mi3 = mnegi(t3);
        a[ai]      = t0 + t1;
        a[ai + 4]  = cmul(t2 + mi3, w1);
        a[ai + 8]  = cmul(t0 - t1, w2);
        a[ai + 12] = cmul(t2 - mi3, w3);
    }
    const v2f v1 = cmul(sq, sq);                  // w10^4
    const v2f v2 = cmul(v1, v1);
    const v2f v3 = cmul(v2, v1);
#pragma unroll
    for (int p = 0; p < 4; ++p) {
        v2f u0 = a[4 * p], u1 = a[4 * p + 1], u2 = a[4 * p + 2], u3 = a[4 * p + 3];
        v2f t0 = u0 + u2, t1 = u1 + u3;
        v2f t2 = u0 - u2, t3 = u1 - u3;
        v2f mi3 = mnegi(t3);
        a[4 * p]     = t0 + t1;
        a[4 * p + 1] = cmul(t2 + mi3, v1);
        a[4 * p + 2] = cmul(t0 - t1, v2);
        a[4 * p + 3] = cmul(t2 - mi3, v3);
    }
}
// -------- fused inverse radix-16 (levels m2 then m1=4*m2); r1 = +j/(16*m2)
__device__ __forceinline__ void dit16(v2f* a, float r1) {
    const v2f w10 = wtw(r1);
    const v2f sq  = cmul(w10, w10);
    const v2f cu  = cmul(sq, w10);
    const v2f v1  = cmul(sq, sq);
    const v2f v2  = cmul(v1, v1);
    const v2f v3  = cmul(v2, v1);
#pragma unroll
    for (int p = 0; p < 4; ++p) {
        v2f b0 = a[4 * p];
        v2f b1 = cmul(a[4 * p + 1], v1);
        v2f b2 = cmul(a[4 * p + 2], v2);
        v2f b3 = cmul(a[4 * p + 3], v3);
        v2f t0 = b0 + b2, t1 = b0 - b2;
        v2f t2 = b1 + b3;
        v2f dd = b3 - b1;
        v2f t3 = mnegi(dd);
        a[4 * p]     = t0 + t2;
        a[4 * p + 1] = t1 + t3;
        a[4 * p + 2] = t0 - t2;
        a[4 * p + 3] = t1 - t3;
    }
#pragma unroll
    for (int ai = 0; ai < 4; ++ai) {
        v2f w1, w2, w3;
        if (ai == 0)      { w1 = w10; w2 = sq; w3 = cu; }
        else if (ai == 1) { w1 = cmul(w10, mk(C1F, S1F));
                            w2 = cmul(sq,  mk(C2F, C2F));
                            w3 = cmul(cu,  mk(S1F, C1F)); }
        else if (ai == 2) { w1 = cmul(w10, mk(C2F, C2F));
                            w2 = mk(-sq.y, sq.x);           // sq * (+i)
                            w3 = cmul(cu,  mk(-C2F, C2F)); }
        else              { w1 = cmul(w10, mk(S1F, C1F));
                            w2 = cmul(sq,  mk(-C2F, C2F));
                            w3 = cmul(cu,  mk(-C1F, -S1F)); }
        v2f b0 = a[ai];
        v2f b1 = cmul(a[ai + 4], w1);
        v2f b2 = cmul(a[ai + 8], w2);
        v2f b3 = cmul(a[ai + 12], w3);
        v2f t0 = b0 + b2, t1 = b0 - b2;
        v2f t2 = b1 + b3;
        v2f dd = b3 - b1;
        v2f t3 = mnegi(dd);
        a[ai]      = t0 + t2;
        a[ai + 4]  = t1 + t3;
        a[ai + 8]  = t0 - t2;
        a[ai + 12] = t1 - t3;
    }
}
__device__ __forceinline__ void fwd4x4(v2f* a) {   // radix-4 DIF, m=1, twiddle-free
#pragma unroll
    for (int u = 0; u < 4; ++u) {
        v2f u0 = a[4*u], u1 = a[4*u+1], u2 = a[4*u+2], u3 = a[4*u+3];
        v2f t0 = u0 + u2, t1 = u1 + u3, t2 = u0 - u2, t3 = u1 - u3;
        v2f mi3 = mnegi(t3);
        a[4*u] = t0 + t1; a[4*u+1] = t2 + mi3;
        a[4*u+2] = t0 - t1; a[4*u+3] = t2 - mi3;
    }
}
__device__ __forceinline__ void inv4x4(v2f* a) {   // inverse radix-4, m=1
#pragma unroll
    for (int u = 0; u < 4; ++u) {
        v2f b0 = a[4*u], b1 = a[4*u+1], b2 = a[4*u+2], b3 = a[4*u+3];
        v2f t0 = b0 + b2, t1 = b0 - b2, t2 = b1 + b3;
        v2f dd = b3 - b1;
        v2f t3 = mnegi(dd);
        a[4*u] = t0 + t2; a[4*u+1] = t1 + t3;
        a[4*u+2] = t0 - t2; a[4*u+3] = t1 - t3;
    }
}

// ======== hspec's forward 8192-pt FFT — round-5-exact path (loads inline, full publish)
__device__ __forceinline__ void fwd8k_h(const v2f* __restrict__ src,
                                        v2f* __restrict__ z, const int w, v2f* a) {
    const float R2 = 0.70710678118654752f;
#pragma unroll
    for (int g = 0; g < 2; ++g) {
        const int i0 = w + 512 * g;
        v2f c0 = src[i0], c1 = src[i0 + 1024], c2 = src[i0 + 2048], c3 = src[i0 + 3072];
        const v2f wA  = wtw(-(float)i0 * (1.0f / 8192.0f));
        const v2f wB  = cmul(wA, wA);
        const v2f wB2 = cmul(wB, wB);
        const v2f wB3 = cmul(wB2, wB);
        const int pb = PHYS(i0);
        v2f t0 = c0 + c2, t1 = c1 + c3, t2 = c0 - c2, t3 = c1 - c3;
        v2f mi3 = mnegi(t3);
        z[pb]            = t0 + t1;
        z[pb + 1088]     = cmul(t2 + mi3, wB);
        z[pb + 2 * 1088] = cmul(t0 - t1, wB2);
        z[pb + 3 * 1088] = cmul(t2 - mi3, wB3);
        v2f d0 = cmul(c0, wA);
        v2f d1 = cmul(c1, cmul(wA, mk(R2, -R2)));
        v2f d2 = cmul(c2, mk(wA.y, -wA.x));           // -i*wA
        v2f d3 = cmul(c3, cmul(wA, mk(-R2, -R2)));
        t0 = d0 + d2; t1 = d1 + d3; t2 = d0 - d2; t3 = d1 - d3;
        mi3 = mnegi(t3);
        z[pb + 4 * 1088] = t0 + t1;
        z[pb + 5 * 1088] = cmul(t2 + mi3, wB);
        z[pb + 6 * 1088] = cmul(t0 - t1, wB2);
        z[pb + 7 * 1088] = cmul(t2 - mi3, wB3);
    }
    __syncthreads();
    {
        const int j = w & 63, blk = w >> 6;
        const int base = PHYS(blk * 1024 + j);
#pragma unroll
        for (int t = 0; t < 16; ++t) a[t] = z[base + 68 * t];
        dif16(a, -(float)j * (1.0f / 1024.0f));
#pragma unroll
        for (int t = 0; t < 16; ++t) z[base + 68 * t] = a[t];
    }
    __syncthreads();
    {
        const int j = w & 3, g = w >> 2;
        const int i0 = g * 64 + j;
#pragma unroll
        for (int t = 0; t < 16; ++t) a[t] = z[PHYS(i0 + 4 * t)];
        dif16(a, -(float)j * (1.0f / 64.0f));
#pragma unroll
        for (int t = 0; t < 16; ++t) z[PHYS(i0 + 4 * t)] = a[t];
    }
    __syncthreads();
    {
        const int base = 17 * w;
#pragma unroll
        for (int t = 0; t < 16; ++t) a[t] = z[base + t];
        fwd4x4(a);
#pragma unroll
        for (int t = 0; t < 16; ++t) z[base + t] = a[t];
    }
    __syncthreads();
}

// ======== main's forward 8192-pt FFT — preloaded c[8], rotation trick, publish 8 non-owner
__device__ __forceinline__ void fwd8k_m(const v2f* __restrict__ c,
                                        v2f* __restrict__ z, const int w, v2f* a) {
    const float R2 = 0.70710678118654752f;
    const v2f wA0 = wtw(-(float)w * (1.0f / 8192.0f));
#pragma unroll
    for (int g = 0; g < 2; ++g) {
        const int i0 = w + 512 * g;
        v2f c0 = c[4*g], c1 = c[4*g+1], c2 = c[4*g+2], c3 = c[4*g+3];
        const v2f wA  = (g == 0) ? wA0 : cmul(wA0, mk(C1F, -S1F));  // rotate by e^{-i*pi/8}
        const v2f wB  = cmul(wA, wA);
        const v2f wB2 = cmul(wB, wB);
        const v2f wB3 = cmul(wB2, wB);
        const int pb = PHYS(i0);
        v2f t0 = c0 + c2, t1 = c1 + c3, t2 = c0 - c2, t3 = c1 - c3;
        v2f mi3 = mnegi(t3);
        z[pb]            = t0 + t1;
        z[pb + 1088]     = cmul(t2 + mi3, wB);
        z[pb + 2 * 1088] = cmul(t0 - t1, wB2);
        z[pb + 3 * 1088] = cmul(t2 - mi3, wB3);
        v2f d0 = cmul(c0, wA);
        v2f d1 = cmul(c1, cmul(wA, mk(R2, -R2)));
        v2f d2 = cmul(c2, mk(wA.y, -wA.x));           // -i*wA
        v2f d3 = cmul(c3, cmul(wA, mk(-R2, -R2)));
        t0 = d0 + d2; t1 = d1 + d3; t2 = d0 - d2; t3 = d1 - d3;
        mi3 = mnegi(t3);
        z[pb + 4 * 1088] = t0 + t1;
        z[pb + 5 * 1088] = cmul(t2 + mi3, wB);
        z[pb + 6 * 1088] = cmul(t0 - t1, wB2);
        z[pb + 7 * 1088] = cmul(t2 - mi3, wB3);
    }
    __syncthreads();
    {
        const int j = w & 63, blk = w >> 6;
        const int base = PHYS(blk * 1024 + j);
#pragma unroll
        for (int t = 0; t < 16; ++t) a[t] = z[base + 68 * t];
        dif16(a, -(float)j * (1.0f / 1024.0f));
#pragma unroll
        for (int t = 0; t < 16; ++t) z[base + 68 * t] = a[t];
    }
    __syncthreads();
    {
        const int j = w & 3, g = w >> 2;
        const int i0 = g * 64 + j;
#pragma unroll
        for (int t = 0; t < 16; ++t) a[t] = z[PHYS(i0 + 4 * t)];
        dif16(a, -(float)j * (1.0f / 64.0f));
#pragma unroll
        for (int t = 0; t < 16; ++t) z[PHYS(i0 + 4 * t)] = a[t];
    }
    __syncthreads();
    {
        const int base = 17 * w;
#pragma unroll
        for (int t = 0; t < 16; ++t) a[t] = z[base + t];
        fwd4x4(a);
#pragma unroll
        for (int t = 0; t < 16; ++t)
            if ((t & 3) > 1) z[base + t] = a[t];     // publish non-owner slots only
    }
    __syncthreads();
}

// ============ kernel 1: per-channel H spectrum, scaled by 1/N, H += B (round-5 exact)
extern "C" __global__ void __launch_bounds__(NTH, 4)
hspec_kernel(const float* __restrict__ hg, const float* __restrict__ bg,
             float* __restrict__ wsHf, float* __restrict__ wsNy) {
    extern __shared__ v2f z[];
    const int w = threadIdx.x;
    const int d = blockIdx.x;
    const v2f* hr = (const v2f*)hg + (size_t)d * 4096;
    v2f a[16];
    fwd8k_h(hr, z, w, a);

    const float Bd = bg[d];
    const float invN = 1.0f / 16384.0f;
    v2f* out = (v2f*)wsHf + (size_t)d * NHALF;
    const int wm = w & 255, whi = w >> 8;
    const int k0 = 2 * drev8(wm) + whi;
    const v2f wk0 = wtw(-(float)k0 * (1.0f / 16384.0f));
    int qm = 0;
    if (w != 0) { const int bq = (512 - k0) >> 1; qm = (whi << 8) | drev8(bq); }
#pragma unroll
    for (int t = 0; t < 16; ++t) {
        const int rt = rtof(t);
        if (w == 0 && t == 0) {
            v2f C0 = a[0];
            out[0] = mk((C0.x + C0.y + Bd) * invN, 0.0f);
            ((v2f*)wsNy)[d] = mk((C0.x - C0.y + Bd) * invN, 0.0f);
        } else {
            const int cq = (w == 0) ? rev2i(16 - rt) : rev2i(15 - rt);
            const v2f Cq = z[17 * qm + cq];
            const v2f Cp = a[t];
            const v2f cA = mk(0.5f * (Cp.x + Cq.x), 0.5f * (Cp.y - Cq.y));
            const v2f cB = mk(0.5f * (Cp.y + Cq.y), -0.5f * (Cp.x - Cq.x));
            const v2f Wk = cmul(wk0, Ktw(rt));
            const v2f Hf = cA + cmul(Wk, cB);
            out[(t << 9) + w] = mk((Hf.x + Bd) * invN, Hf.y * invN);
        }
    }
}

// ============ kernel 2: main conv — lazy H reads in P4b (r5-style), PUB8 + rotation kept
extern "C" __global__ void __launch_bounds__(NTH, 4)
fftconv_main(const float* __restrict__ xg, const float* __restrict__ wsHf,
             const float* __restrict__ wsNy, float* __restrict__ yg) {
    extern __shared__ v2f z[];
    const int w = threadIdx.x;
    const int bid = blockIdx.x;
    const int d = bid >> 2, b = bid & 3;
    const v2f* xr = (const v2f*)xg + (size_t)(b * DCH + d) * 4096;
    const v2f* hrow = (const v2f*)wsHf + (size_t)d * NHALF;
    const float R2 = 0.70710678118654752f;
    v2f a[16], c[8];

#pragma unroll
    for (int g = 0; g < 2; ++g)
#pragma unroll
        for (int t = 0; t < 4; ++t) c[4*g + t] = xr[w + 512*g + 1024*t];

    fwd8k_m(c, z, w, a);

    // ---- P4b: pair-owner combine; owner Wtil stays in regs, partner to LDS.
    // H reads are LAZY (inside the loop) — staggered across block progress,
    // avoiding the launch-time gather burst against hspec's draining writes.
    {
        const int wm = w & 255, whi = w >> 8;
        const int k0 = 2 * drev8(wm) + whi;
        const v2f wk0 = wtw(-(float)k0 * (1.0f / 16384.0f));
        int qm = 0;
        if (w != 0) { const int bq = (512 - k0) >> 1; qm = (whi << 8) | drev8(bq); }
#pragma unroll
        for (int t = 0; t < 16; ++t) {
            if ((t & 3) > 1) continue;           // owner elements: rt < 8
            const int rt = rtof(t);
            if (w == 0 && t == 0) {
                v2f C0 = a[0];
                float X0 = C0.x + C0.y, XN = C0.x - C0.y;
                v2f H0 = hrow[0];
                v2f HN = ((const v2f*)wsNy)[d];
                v2f Y1 = mk(X0 * H0.x, X0 * H0.y);
                v2f Y2 = mk(XN * HN.x, XN * HN.y);
                v2f S  = mk(Y1.x + Y2.x, Y1.y - Y2.y);
                v2f Dd = mk(Y1.x - Y2.x, Y1.y + Y2.y);
                a[0] = mk(S.x - Dd.y, S.y + Dd.x);
            } else {
                const int cq = (w == 0) ? rev2i(16 - rt) : rev2i(15 - rt);
                const v2f Cq = z[17 * qm + cq];
                const v2f Cp = a[t];
                const v2f cA = mk(0.5f * (Cp.x + Cq.x), 0.5f * (Cp.y - Cq.y));
                const v2f cB = mk(0.5f * (Cp.y + Cq.y), -0.5f * (Cp.x - Cq.x));
                const v2f Wk = cmul(wk0, Ktw(rt));
                const v2f T  = cmul(Wk, cB);
                const v2f X1 = cA + T;
                const v2f X2 = mk(cA.x - T.x, -(cA.y - T.y));  // conj(cA - T)
                const v2f Hp = hrow[(t << 9) + w];
                const v2f Hq = hrow[(cq << 9) + qm];
                const v2f Y1 = cmul(X1, Hp);
                const v2f Y2 = cmul(X2, Hq);
                const v2f S  = mk(Y1.x + Y2.x, Y1.y - Y2.y);
                const v2f Dd = mk(Y1.x - Y2.x, Y1.y + Y2.y);
                const v2f Vk = mk(Wk.x, -Wk.y);
                const v2f U  = cmul(Vk, Dd);
                a[t]            = mk(S.x - U.y, S.y + U.x);     // own Wtil[k]
                z[17 * qm + cq] = mk(S.x + U.y, U.x - S.y);     // partner Wtil
            }
        }
        if (w == 0) {   // self-pair k = 4096 (position 2)
            const v2f Cp = z[2];
            const v2f cA = mk(Cp.x, 0.0f);
            const v2f cB = mk(Cp.y, 0.0f);
            const v2f Wk = mk(0.0f, -1.0f);
            const v2f T  = cmul(Wk, cB);
            const v2f X1 = cA + T;
            const v2f X2 = mk(cA.x - T.x, -(cA.y - T.y));
            const v2f Hp = hrow[(2 << 9)];
            const v2f Y1 = cmul(X1, Hp);
            const v2f Y2 = cmul(X2, Hp);
            const v2f S  = mk(Y1.x + Y2.x, Y1.y - Y2.y);
            const v2f Dd = mk(Y1.x - Y2.x, Y1.y + Y2.y);
            const v2f Vk = mk(0.0f, 1.0f);
            const v2f U  = cmul(Vk, Dd);
            z[2] = mk(S.x - U.y, S.y + U.x);
        }
    }
    __syncthreads();
    // ---- inverse radix-4 (m=1): own 8 from regs, missing 8 from LDS
    {
        const int base = 17 * w;
#pragma unroll
        for (int t = 0; t < 16; ++t)
            if ((t & 3) > 1) a[t] = z[base + t];
        inv4x4(a);
#pragma unroll
        for (int t = 0; t < 16; ++t) z[base + t] = a[t];
    }
    __syncthreads();
    // ---- P5: inverse radix-16, m2 = 4
    {
        const int j = w & 3, g = w >> 2;
        const int i0 = g * 64 + j;
#pragma unroll
        for (int t = 0; t < 16; ++t) a[t] = z[PHYS(i0 + 4 * t)];
        dit16(a, (float)j * (1.0f / 64.0f));
#pragma unroll
        for (int t = 0; t < 16; ++t) z[PHYS(i0 + 4 * t)] = a[t];
    }
    __syncthreads();
    // ---- P6: inverse radix-16, m2 = 64
    {
        const int j = w & 63, blk = w >> 6;
        const int base = PHYS(blk * 1024 + j);
#pragma unroll
        for (int t = 0; t < 16; ++t) a[t] = z[base + 68 * t];
        dit16(a, (float)j * (1.0f / 1024.0f));
#pragma unroll
        for (int t = 0; t < 16; ++t) z[base + 68 * t] = a[t];
    }
    __syncthreads();
    // ---- P7: inverse radix-4(m=1024) + inverse radix-2(m=4096), store y
    {
        v2f* yr = (v2f*)yg + (size_t)(b * DCH + d) * 4096;
        const v2f vA0 = wtw((float)w * (1.0f / 8192.0f));
#pragma unroll
        for (int g = 0; g < 2; ++g) {
            const int i0 = w + 512 * g;
            const int pb = PHYS(i0);
            v2f q0 = z[pb],            q1 = z[pb + 1088],
                q2 = z[pb + 2 * 1088], q3 = z[pb + 3 * 1088],
                q4 = z[pb + 4 * 1088], q5 = z[pb + 5 * 1088],
                q6 = z[pb + 6 * 1088], q7 = z[pb + 7 * 1088];
            const v2f vA  = (g == 0) ? vA0 : cmul(vA0, mk(C1F, S1F));  // rotate e^{+i*pi/8}
            const v2f vB  = cmul(vA, vA);
            const v2f vB2 = cmul(vB, vB);
            const v2f vB3 = cmul(vB2, vB);
            v2f b1 = cmul(q1, vB), b2 = cmul(q2, vB2), b3 = cmul(q3, vB3);
            v2f t0 = q0 + b2, t1 = q0 - b2, t2 = b1 + b3;
            v2f dd = b3 - b1;
            v2f t3 = mnegi(dd);
            v2f T0 = t0 + t2, T1 = t1 + t3, T2 = t0 - t2, T3 = t1 - t3;
            b1 = cmul(q5, vB); b2 = cmul(q6, vB2); b3 = cmul(q7, vB3);
            t0 = q4 + b2; t1 = q4 - b2; t2 = b1 + b3;
            dd = b3 - b1;
            t3 = mnegi(dd);
            v2f B0 = t0 + t2, B1 = t1 + t3, B2 = t0 - t2, B3 = t1 - t3;
            yr[i0]        = T0 + cmul(B0, vA);
            yr[i0 + 1024] = T1 + cmul(B1, cmul(vA, mk(R2, R2)));
            yr[i0 + 2048] = T2 + cmul(B2, mk(-vA.y, vA.x));   // i*vA
            yr[i0 + 3072] = T3 + cmul(B3, cmul(vA, mk(-R2, R2)));
        }
    }
}

// ===================== fallback: verified 16K-FFT single-kernel path =====================
__device__ __forceinline__ int drev14(int v) {
    int r = 0;
#pragma unroll
    for (int i = 0; i < 7; ++i) { r = (r << 2) | (v & 3); v >>= 2; }
    return r;
}
__device__ __forceinline__ int drev10(int v) {
    int r = 0;
#pragma unroll
    for (int i = 0; i < 5; ++i) { r = (r << 2) | (v & 3); v >>= 2; }
    return r;
}

extern "C" __global__ void __launch_bounds__(NTH2, 4)
fftconv_v2(const float* __restrict__ hg, const float* __restrict__ xg,
           const float* __restrict__ bg, float* __restrict__ yg) {
    extern __shared__ v2f z[];
    const int w = threadIdx.x;
    const int bid = blockIdx.x;
    const int d = bid >> 2, b = bid & 3;
    const float* xr = xg + (size_t)(b * DCH + d) * 8192;
    const float* hr = hg + (size_t)d * 8192;
    v2f a[16];
    float xv[8];
    {
#pragma unroll
        for (int t = 0; t < 8; ++t) {
            xv[t] = xr[w + 1024 * t];
            float hv = hr[w + 1024 * t];
            a[t] = mk(xv[t], hv);
        }
        const float r1 = -(float)w * (1.0f / 16384.0f);
#pragma unroll
        for (int ai = 0; ai < 4; ++ai) {
            v2f u0 = a[ai], u1 = a[ai + 4];
            v2f mi3 = mk(u1.y, -u1.x);
            v2f w1 = wtw(r1 - 0.0625f * ai);
            v2f w2 = cmul(w1, w1), w3 = cmul(w2, w1);
            a[ai]      = u0 + u1;
            a[ai + 4]  = cmul(u0 + mi3, w1);
            a[ai + 8]  = cmul(u0 - u1, w2);
            a[ai + 12] = cmul(u0 - mi3, w3);
        }
        v2f v1 = wtw(4.0f * r1);
        v2f v2 = cmul(v1, v1), v3 = cmul(v2, v1);
#pragma unroll
        for (int p = 0; p < 4; ++p) {
            v2f u0 = a[4 * p], u1 = a[4 * p + 1], u2 = a[4 * p + 2], u3 = a[4 * p + 3];
            v2f t0 = u0 + u2, t1 = u1 + u3;
            v2f t2 = u0 - u2, t3 = u1 - u3;
            v2f mi3 = mnegi(t3);
            a[4 * p]     = t0 + t1;
            a[4 * p + 1] = cmul(t2 + mi3, v1);
            a[4 * p + 2] = cmul(t0 - t1, v2);
            a[4 * p + 3] = cmul(t2 - mi3, v3);
        }
        const int base = PHYS(w);
#pragma unroll
        for (int t = 0; t < 16; ++t) z[base + 1088 * t] = a[t];
    }
    __syncthreads();
    {
        const int j = w & 63, grp = w >> 6;
        const int base = PHYS(grp * 1024 + j);
#pragma unroll
        for (int t = 0; t < 16; ++t) a[t] = z[base + 68 * t];
        dif16(a, -(float)j * (1.0f / 1024.0f));
#pragma unroll
        for (int t = 0; t < 16; ++t) z[base + 68 * t] = a[t];
    }
    __syncthreads();
    {
        const int j = w & 3, grp = w >> 2;
        const int i0 = grp * 64 + j;
#pragma unroll
        for (int t = 0; t < 16; ++t) a[t] = z[PHYS(i0 + 4 * t)];
        dif16(a, -(float)j * (1.0f / 64.0f));
#pragma unroll
        for (int t = 0; t < 16; ++t) z[PHYS(i0 + 4 * t)] = a[t];
    }
    __syncthreads();
    {
        const int base = 17 * w;
#pragma unroll
        for (int t = 0; t < 16; ++t) a[t] = z[base + t];
        fwd4x4(a);
#pragma unroll
        for (int t = 0; t < 16; ++t) z[base + t] = a[t];
        __syncthreads();
        const int kw = drev10(w);
#pragma unroll
        for (int t = 0; t < 16; ++t) {
            const int rt = (((t & 3) << 2) | (t >> 2));
            const int k = (rt << 10) | kw;
            const int pp = drev14(16384 - k);
            const v2f Zm = z[PHYS(pp)];
            const v2f Zp = a[t];
            const v2f A  = mk(Zp.x + Zm.x, Zp.y - Zm.y);
            const v2f Dv = mk(Zp.x - Zm.x, Zp.y + Zm.y);
            const v2f X  = mk(0.5f * A.x, 0.5f * A.y);
            const v2f H  = mk(0.5f * Dv.y, -0.5f * Dv.x);
            a[t] = cmul(X, H);
        }
        __syncthreads();
        inv4x4(a);
#pragma unroll
        for (int t = 0; t < 16; ++t) z[base + t] = a[t];
    }
    __syncthreads();
    {
        const int j = w & 3, grp = w >> 2;
        const int i0 = grp * 64 + j;
#pragma unroll
        for (int t = 0; t < 16; ++t) a[t] = z[PHYS(i0 + 4 * t)];
        dit16(a, (float)j * (1.0f / 64.0f));
#pragma unroll
        for (int t = 0; t < 16; ++t) z[PHYS(i0 + 4 * t)] = a[t];
    }
    __syncthreads();
    {
        const int j = w & 63, grp = w >> 6;
        const int base = PHYS(grp * 1024 + j);
#pragma unroll
        for (int t = 0; t < 16; ++t) a[t] = z[base + 68 * t];
        dit16(a, (float)j * (1.0f / 1024.0f));
#pragma unroll
        for (int t = 0; t < 16; ++t) z[base + 68 * t] = a[t];
    }
    __syncthreads();
    {
        const int base = PHYS(w);
#pragma unroll
        for (int t = 0; t < 16; ++t) a[t] = z[base + 1088 * t];
        const float r1 = (float)w * (1.0f / 16384.0f);
        v2f v1 = wtw(4.0f * r1);
        v2f v2 = cmul(v1, v1), v3 = cmul(v2, v1);
#pragma unroll
        for (int p = 0; p < 4; ++p) {
            v2f b0 = a[4 * p];
            v2f b1 = cmul(a[4 * p + 1], v1);
            v2f b2 = cmul(a[4 * p + 2], v2);
            v2f b3 = cmul(a[4 * p + 3], v3);
            v2f t0 = b0 + b2, t1 = b0 - b2;
            v2f t2 = b1 + b3;
            v2f dd = b3 - b1;
            v2f t3 = mnegi(dd);
            a[4 * p]     = t0 + t2;
            a[4 * p + 1] = t1 + t3;
            a[4 * p + 2] = t0 - t2;
            a[4 * p + 3] = t1 - t3;
        }
        const float bd = bg[d];
        const float invN = 1.0f / 16384.0f;
#pragma unroll
        for (int ai = 0; ai < 4; ++ai) {
            v2f w1 = wtw(r1 + 0.0625f * ai);
            v2f w2 = cmul(w1, w1), w3 = cmul(w2, w1);
            v2f b0 = a[ai];
            v2f vv1 = cmul(a[ai + 4], w1);
            v2f vv2 = cmul(a[ai + 8], w2);
            v2f vv3 = cmul(a[ai + 12], w3);
            v2f t0 = b0 + vv2, t1 = b0 - vv2;
            v2f t2 = vv1 + vv3;
            v2f dd = vv3 - vv1;
            v2f t3 = mnegi(dd);
            v2f o0 = t0 + t2;
            v2f o1 = t1 + t3;
            yg[(size_t)(b * DCH + d) * 8192 + w + 1024 * ai]        = fmaf(xv[ai], bd, o0.x * invN);
            yg[(size_t)(b * DCH + d) * 8192 + w + 4096 + 1024 * ai] = fmaf(xv[ai + 4], bd, o1.x * invN);
        }
    }
}

extern "C" void kernel_launch(void* const* d_in, const int* in_sizes, int n_in,
                              void* d_out, int out_size, void* d_ws, size_t ws_size,
                              hipStream_t stream) {
    (void)in_sizes; (void)n_in; (void)out_size;
    const float* h = (const float*)d_in[0];
    const float* x = (const float*)d_in[1];
    const float* B = (const float*)d_in[2];
    float* y = (float*)d_out;

    const size_t need = (size_t)(DCH * NHALF + DCH) * sizeof(float2);
    if (ws_size >= need && d_ws != nullptr) {
        (void)hipFuncSetAttribute((const void*)hspec_kernel,
                                  hipFuncAttributeMaxDynamicSharedMemorySize,
                                  LDSE * (int)sizeof(float2));
        (void)hipFuncSetAttribute((const void*)fftconv_main,
                                  hipFuncAttributeMaxDynamicSharedMemorySize,
                                  LDSE * (int)sizeof(float2));
        float* wsHf = (float*)d_ws;
        float* wsNy = wsHf + 2 * (size_t)DCH * NHALF;
        hspec_kernel<<<dim3(DCH), dim3(NTH), LDSE * sizeof(float2), stream>>>(h, B, wsHf, wsNy);
        fftconv_main<<<dim3(4 * DCH), dim3(NTH), LDSE * sizeof(float2), stream>>>(x, wsHf, wsNy, y);
    } else {
        (void)hipFuncSetAttribute((const void*)fftconv_v2,
                                  hipFuncAttributeMaxDynamicSharedMemorySize,
                                  LDSE2 * (int)sizeof(float2));
        fftconv_v2<<<dim3(4 * DCH), dim3(NTH2), LDSE2 * sizeof(float2), stream>>>(h, x, B, y);
    }
}